// Round 1
// baseline (2189.713 us; speedup 1.0000x reference)
//
#include <hip/hip_runtime.h>

// Problem constants (SimVQ): x[8,2048,512] f32, codebook[8192,512] f32, W[512,512] f32
// Outputs concatenated in d_out (float32): quantized[8*2048*512], indices[8*2048] (as float),
// commit_loss[1]. Rotation-trick forward value == gathered code q exactly (algebraic identity),
// so output 0 is codes[idx].
#define DIMK   512
#define CBN    8192
#define MROWS  16384

// ws layout (bytes):
//   codes   @ 0          : 8192*512*4 = 16,777,216
//   norms   @ 16,777,216 : 8192*4     = 32,768
//   packed  @ 16,809,984 : 16384*8    = 131,072   (u64: key<<32 | idx)
//   loss    @ 16,941,056 : 4
#define WS_NORMS   16777216
#define WS_PACKED  16809984
#define WS_LOSS    16941056

#define BM 64
#define BN 64
#define BK 16

__device__ __forceinline__ unsigned long long packMin(float f, unsigned idx) {
    unsigned u = __float_as_uint(f);
    // monotonic float -> ordered uint mapping
    u = (u & 0x80000000u) ? ~u : (u | 0x80000000u);
    return (((unsigned long long)u) << 32) | (unsigned long long)idx;
}

__device__ __forceinline__ unsigned long long u64min(unsigned long long a, unsigned long long b) {
    return (b < a) ? b : a;
}

// C[m,n] = sum_k A[m,k] * B[n,k]   (A:[M,512] row-major, B:[N,512] row-major)
// Used for codes = codebook @ W^T  (M=8192, N=512)
__global__ __launch_bounds__(256) void codes_gemm(const float* __restrict__ A,
                                                  const float* __restrict__ B,
                                                  float* __restrict__ C) {
    __shared__ float As[BK][BM];
    __shared__ float Bs[BK][BN];
    const int t  = threadIdx.x;
    const int tx = t & 15, ty = t >> 4;
    const int rowBase = blockIdx.x * BM;
    const int colBase = blockIdx.y * BN;
    const int lr = t >> 2;          // 0..63
    const int lk = (t & 3) << 2;    // 0,4,8,12

    float4 c0 = make_float4(0,0,0,0), c1 = c0, c2 = c0, c3 = c0;

    const float* Ap = A + (size_t)(rowBase + lr) * DIMK + lk;
    const float* Bp = B + (size_t)(colBase + lr) * DIMK + lk;

    for (int k0 = 0; k0 < DIMK; k0 += BK) {
        float4 av = *(const float4*)(Ap + k0);
        float4 bv = *(const float4*)(Bp + k0);
        As[lk + 0][lr] = av.x; As[lk + 1][lr] = av.y; As[lk + 2][lr] = av.z; As[lk + 3][lr] = av.w;
        Bs[lk + 0][lr] = bv.x; Bs[lk + 1][lr] = bv.y; Bs[lk + 2][lr] = bv.z; Bs[lk + 3][lr] = bv.w;
        __syncthreads();
        #pragma unroll
        for (int k = 0; k < BK; ++k) {
            float4 a = *(const float4*)&As[k][ty << 2];   // 4 rows
            float4 b = *(const float4*)&Bs[k][tx << 2];   // 4 cols
            c0.x = fmaf(a.x, b.x, c0.x); c0.y = fmaf(a.x, b.y, c0.y); c0.z = fmaf(a.x, b.z, c0.z); c0.w = fmaf(a.x, b.w, c0.w);
            c1.x = fmaf(a.y, b.x, c1.x); c1.y = fmaf(a.y, b.y, c1.y); c1.z = fmaf(a.y, b.z, c1.z); c1.w = fmaf(a.y, b.w, c1.w);
            c2.x = fmaf(a.z, b.x, c2.x); c2.y = fmaf(a.z, b.y, c2.y); c2.z = fmaf(a.z, b.z, c2.z); c2.w = fmaf(a.z, b.w, c2.w);
            c3.x = fmaf(a.w, b.x, c3.x); c3.y = fmaf(a.w, b.y, c3.y); c3.z = fmaf(a.w, b.z, c3.z); c3.w = fmaf(a.w, b.w, c3.w);
        }
        __syncthreads();
    }
    const int r0 = rowBase + (ty << 2);
    const int cc = colBase + (tx << 2);
    *(float4*)(C + (size_t)(r0 + 0) * 512 + cc) = c0;
    *(float4*)(C + (size_t)(r0 + 1) * 512 + cc) = c1;
    *(float4*)(C + (size_t)(r0 + 2) * 512 + cc) = c2;
    *(float4*)(C + (size_t)(r0 + 3) * 512 + cc) = c3;
}

__global__ __launch_bounds__(128) void norms_kernel(const float* __restrict__ codes,
                                                    float* __restrict__ norms) {
    const int row = blockIdx.x;
    const int t = threadIdx.x;  // 128
    float4 v = *(const float4*)(codes + (size_t)row * DIMK + (t << 2));
    float s = v.x * v.x + v.y * v.y + v.z * v.z + v.w * v.w;
    #pragma unroll
    for (int off = 32; off > 0; off >>= 1) s += __shfl_down(s, off);
    __shared__ float red[2];
    if ((t & 63) == 0) red[t >> 6] = s;
    __syncthreads();
    if (t == 0) norms[row] = red[0] + red[1];
}

// d2[m,c] = norms[c] - 2 * sum_k X[m,k]*Codes[c,k]; block-local argmin over its 64 codes,
// then atomicMin merge into Packed[m].
__global__ __launch_bounds__(256) void d2_argmin(const float* __restrict__ X,
                                                 const float* __restrict__ Codes,
                                                 const float* __restrict__ Norms,
                                                 unsigned long long* __restrict__ Packed) {
    __shared__ float As[BK][BM];
    __shared__ float Bs[BK][BN];
    __shared__ unsigned long long Red[BM][16];
    const int t  = threadIdx.x;
    const int tx = t & 15, ty = t >> 4;
    const int rowBase = blockIdx.x * BM;
    const int colBase = blockIdx.y * BN;
    const int lr = t >> 2;
    const int lk = (t & 3) << 2;

    float4 c0 = make_float4(0,0,0,0), c1 = c0, c2 = c0, c3 = c0;

    const float* Ap = X + (size_t)(rowBase + lr) * DIMK + lk;
    const float* Bp = Codes + (size_t)(colBase + lr) * DIMK + lk;

    for (int k0 = 0; k0 < DIMK; k0 += BK) {
        float4 av = *(const float4*)(Ap + k0);
        float4 bv = *(const float4*)(Bp + k0);
        As[lk + 0][lr] = av.x; As[lk + 1][lr] = av.y; As[lk + 2][lr] = av.z; As[lk + 3][lr] = av.w;
        Bs[lk + 0][lr] = bv.x; Bs[lk + 1][lr] = bv.y; Bs[lk + 2][lr] = bv.z; Bs[lk + 3][lr] = bv.w;
        __syncthreads();
        #pragma unroll
        for (int k = 0; k < BK; ++k) {
            float4 a = *(const float4*)&As[k][ty << 2];
            float4 b = *(const float4*)&Bs[k][tx << 2];
            c0.x = fmaf(a.x, b.x, c0.x); c0.y = fmaf(a.x, b.y, c0.y); c0.z = fmaf(a.x, b.z, c0.z); c0.w = fmaf(a.x, b.w, c0.w);
            c1.x = fmaf(a.y, b.x, c1.x); c1.y = fmaf(a.y, b.y, c1.y); c1.z = fmaf(a.y, b.z, c1.z); c1.w = fmaf(a.y, b.w, c1.w);
            c2.x = fmaf(a.z, b.x, c2.x); c2.y = fmaf(a.z, b.y, c2.y); c2.z = fmaf(a.z, b.z, c2.z); c2.w = fmaf(a.z, b.w, c2.w);
            c3.x = fmaf(a.w, b.x, c3.x); c3.y = fmaf(a.w, b.y, c3.y); c3.z = fmaf(a.w, b.z, c3.z); c3.w = fmaf(a.w, b.w, c3.w);
        }
        __syncthreads();
    }

    const int cc = colBase + (tx << 2);
    float4 nv = *(const float4*)(Norms + cc);

    #pragma unroll
    for (int i = 0; i < 4; ++i) {
        float4 acc = (i == 0) ? c0 : (i == 1) ? c1 : (i == 2) ? c2 : c3;
        float d0 = fmaf(-2.f, acc.x, nv.x);
        float d1 = fmaf(-2.f, acc.y, nv.y);
        float d2v = fmaf(-2.f, acc.z, nv.z);
        float d3 = fmaf(-2.f, acc.w, nv.w);
        unsigned long long m = packMin(d0, cc + 0);
        m = u64min(m, packMin(d1, cc + 1));
        m = u64min(m, packMin(d2v, cc + 2));
        m = u64min(m, packMin(d3, cc + 3));
        Red[(ty << 2) + i][tx] = m;
    }
    __syncthreads();
    if (t < BM) {
        unsigned long long m = Red[t][0];
        #pragma unroll
        for (int j = 1; j < 16; ++j) m = u64min(m, Red[t][j]);
        atomicMin(&Packed[rowBase + t], m);
    }
}

__global__ __launch_bounds__(128) void gather_loss(const float* __restrict__ X,
                                                   const float* __restrict__ Codes,
                                                   const unsigned long long* __restrict__ Packed,
                                                   float* __restrict__ outQ,
                                                   float* __restrict__ outIdx,
                                                   float* __restrict__ lossAccum) {
    const int row = blockIdx.x;
    const int t = threadIdx.x;  // 128
    const unsigned idx = (unsigned)(Packed[row] & 0xFFFFFFFFull);
    float4 q  = *(const float4*)(Codes + (size_t)idx * DIMK + (t << 2));
    float4 xv = *(const float4*)(X + (size_t)row * DIMK + (t << 2));
    *(float4*)(outQ + (size_t)row * DIMK + (t << 2)) = q;
    float dx = xv.x - q.x, dy = xv.y - q.y, dz = xv.z - q.z, dw = xv.w - q.w;
    float s = dx * dx + dy * dy + dz * dz + dw * dw;
    #pragma unroll
    for (int off = 32; off > 0; off >>= 1) s += __shfl_down(s, off);
    __shared__ float red[2];
    if ((t & 63) == 0) red[t >> 6] = s;
    __syncthreads();
    if (t == 0) {
        atomicAdd(lossAccum, red[0] + red[1]);
        outIdx[row] = (float)idx;
    }
}

__global__ void finalize_loss(const float* __restrict__ lossAccum, float* __restrict__ outLoss) {
    *outLoss = *lossAccum * (1.0f / (float)(MROWS * DIMK));
}

extern "C" void kernel_launch(void* const* d_in, const int* in_sizes, int n_in,
                              void* d_out, int out_size, void* d_ws, size_t ws_size,
                              hipStream_t stream) {
    const float* x  = (const float*)d_in[0];   // [16384, 512]
    const float* cb = (const float*)d_in[1];   // [8192, 512]
    const float* W  = (const float*)d_in[2];   // [512, 512]
    float* out = (float*)d_out;

    char* ws = (char*)d_ws;
    float* codes = (float*)ws;
    float* norms = (float*)(ws + WS_NORMS);
    unsigned long long* packed = (unsigned long long*)(ws + WS_PACKED);
    float* loss = (float*)(ws + WS_LOSS);

    // init scratch (capture-safe async memsets)
    hipMemsetAsync(packed, 0xFF, (size_t)MROWS * 8, stream);   // u64 max
    hipMemsetAsync(loss, 0, 4, stream);

    // codes = codebook @ W^T   [8192, 512]
    codes_gemm<<<dim3(CBN / BM, 512 / BN), 256, 0, stream>>>(cb, W, codes);
    // ||codes||^2 per row
    norms_kernel<<<CBN, 128, 0, stream>>>(codes, norms);
    // fused distance GEMM + argmin
    d2_argmin<<<dim3(MROWS / BM, CBN / BN), 256, 0, stream>>>(x, codes, norms, packed);
    // gather quantized (rotation forward == q), indices, commit loss
    gather_loss<<<MROWS, 128, 0, stream>>>(x, codes, packed, out, out + (size_t)MROWS * DIMK, loss);
    finalize_loss<<<1, 1, 0, stream>>>(loss, out + (size_t)MROWS * DIMK + MROWS);
}

// Round 2
// 780.904 us; speedup vs baseline: 2.8041x; 2.8041x over previous
//
#include <hip/hip_runtime.h>

// SimVQ: x[8,2048,512] f32, codebook[8192,512] f32, W[512,512] f32
// out = concat(quantized[16384*512], indices[16384] (as f32), commit_loss[1])
// Rotation-trick forward value == gathered code exactly, so quantized = codes[idx].
//
// Round 2: distance GEMM on MFMA via bf16 hi/lo split (3 passes: hh + hl + lh).
// m97-style 128x128 tile, BK=32, global_load_lds width-16 staging.

#define DIMK  512
#define CBN   8192
#define MROWS 16384

// ws layout (bytes)
#define WS_CODES   0UL                       // 8192*512*4  = 16,777,216
#define WS_XHI     16777216UL                // 16384*512*2 = 16,777,216
#define WS_XLO     33554432UL
#define WS_CHI     50331648UL                // 8192*512*2  = 8,388,608
#define WS_CLO     58720256UL
#define WS_NORMS   67108864UL                // 8192*4
#define WS_PACKED  67141632UL                // 16384*8
#define WS_LOSS    67272704UL                // 4

typedef short s16x8 __attribute__((ext_vector_type(8)));
typedef float f32x4 __attribute__((ext_vector_type(4)));

__device__ __forceinline__ unsigned short f2bf(float f) {
    unsigned u = __float_as_uint(f);
    unsigned r = u + 0x7FFFu + ((u >> 16) & 1u);   // RTNE
    return (unsigned short)(r >> 16);
}
__device__ __forceinline__ float bf2f(unsigned short h) {
    return __uint_as_float(((unsigned)h) << 16);
}

__device__ __forceinline__ unsigned long long packMin(float f, unsigned idx) {
    unsigned u = __float_as_uint(f);
    u = (u & 0x80000000u) ? ~u : (u | 0x80000000u);   // monotone float->uint
    return (((unsigned long long)u) << 32) | (unsigned long long)idx;
}
__device__ __forceinline__ unsigned long long u64min(unsigned long long a, unsigned long long b) {
    return (b < a) ? b : a;
}

__device__ __forceinline__ void load_lds16(const void* g, void* l) {
    __builtin_amdgcn_global_load_lds((const __attribute__((address_space(1))) void*)g,
                                     (__attribute__((address_space(3))) void*)l,
                                     16, 0, 0);
}

// ---------------- split f32 -> bf16 hi + bf16 lo ----------------
__global__ __launch_bounds__(256) void split_bf16(const float* __restrict__ in,
                                                  unsigned short* __restrict__ hi,
                                                  unsigned short* __restrict__ lo,
                                                  int n4) {
    int i = blockIdx.x * 256 + threadIdx.x;
    if (i >= n4) return;
    float4 v = ((const float4*)in)[i];
    ushort4 h, l;
    h.x = f2bf(v.x); l.x = f2bf(v.x - bf2f(h.x));
    h.y = f2bf(v.y); l.y = f2bf(v.y - bf2f(h.y));
    h.z = f2bf(v.z); l.z = f2bf(v.z - bf2f(h.z));
    h.w = f2bf(v.w); l.w = f2bf(v.w - bf2f(h.w));
    ((ushort4*)hi)[i] = h;
    ((ushort4*)lo)[i] = l;
}

// ---------------- codes = codebook @ W^T (f32, exact for outputs) ----------------
#define BM 64
#define BN 64
#define BK 16
__global__ __launch_bounds__(256) void codes_gemm(const float* __restrict__ A,
                                                  const float* __restrict__ B,
                                                  float* __restrict__ C) {
    __shared__ float As[BK][BM];
    __shared__ float Bs[BK][BN];
    const int t  = threadIdx.x;
    const int tx = t & 15, ty = t >> 4;
    const int rowBase = blockIdx.x * BM;
    const int colBase = blockIdx.y * BN;
    const int lr = t >> 2;
    const int lk = (t & 3) << 2;

    float4 c0 = make_float4(0,0,0,0), c1 = c0, c2 = c0, c3 = c0;
    const float* Ap = A + (size_t)(rowBase + lr) * DIMK + lk;
    const float* Bp = B + (size_t)(colBase + lr) * DIMK + lk;

    for (int k0 = 0; k0 < DIMK; k0 += BK) {
        float4 av = *(const float4*)(Ap + k0);
        float4 bv = *(const float4*)(Bp + k0);
        As[lk + 0][lr] = av.x; As[lk + 1][lr] = av.y; As[lk + 2][lr] = av.z; As[lk + 3][lr] = av.w;
        Bs[lk + 0][lr] = bv.x; Bs[lk + 1][lr] = bv.y; Bs[lk + 2][lr] = bv.z; Bs[lk + 3][lr] = bv.w;
        __syncthreads();
        #pragma unroll
        for (int k = 0; k < BK; ++k) {
            float4 a = *(const float4*)&As[k][ty << 2];
            float4 b = *(const float4*)&Bs[k][tx << 2];
            c0.x = fmaf(a.x, b.x, c0.x); c0.y = fmaf(a.x, b.y, c0.y); c0.z = fmaf(a.x, b.z, c0.z); c0.w = fmaf(a.x, b.w, c0.w);
            c1.x = fmaf(a.y, b.x, c1.x); c1.y = fmaf(a.y, b.y, c1.y); c1.z = fmaf(a.y, b.z, c1.z); c1.w = fmaf(a.y, b.w, c1.w);
            c2.x = fmaf(a.z, b.x, c2.x); c2.y = fmaf(a.z, b.y, c2.y); c2.z = fmaf(a.z, b.z, c2.z); c2.w = fmaf(a.z, b.w, c2.w);
            c3.x = fmaf(a.w, b.x, c3.x); c3.y = fmaf(a.w, b.y, c3.y); c3.z = fmaf(a.w, b.z, c3.z); c3.w = fmaf(a.w, b.w, c3.w);
        }
        __syncthreads();
    }
    const int r0 = rowBase + (ty << 2);
    const int cc = colBase + (tx << 2);
    *(float4*)(C + (size_t)(r0 + 0) * 512 + cc) = c0;
    *(float4*)(C + (size_t)(r0 + 1) * 512 + cc) = c1;
    *(float4*)(C + (size_t)(r0 + 2) * 512 + cc) = c2;
    *(float4*)(C + (size_t)(r0 + 3) * 512 + cc) = c3;
}

__global__ __launch_bounds__(128) void norms_kernel(const float* __restrict__ codes,
                                                    float* __restrict__ norms) {
    const int row = blockIdx.x;
    const int t = threadIdx.x;
    float4 v = *(const float4*)(codes + (size_t)row * DIMK + (t << 2));
    float s = v.x * v.x + v.y * v.y + v.z * v.z + v.w * v.w;
    #pragma unroll
    for (int off = 32; off > 0; off >>= 1) s += __shfl_down(s, off);
    __shared__ float red[2];
    if ((t & 63) == 0) red[t >> 6] = s;
    __syncthreads();
    if (t == 0) norms[row] = red[0] + red[1];
}

// ---------------- fused distance GEMM (MFMA bf16 hi/lo) + argmin ----------------
// grid: (MROWS/128, CBN/128), 256 threads (4 waves, 2x2 of 64x64 each)
__global__ __launch_bounds__(256) void d2_argmin_mfma(
        const unsigned short* __restrict__ Xhi, const unsigned short* __restrict__ Xlo,
        const unsigned short* __restrict__ Chi, const unsigned short* __restrict__ Clo,
        const float* __restrict__ Norms, unsigned long long* __restrict__ Packed) {
    __shared__ __align__(16) unsigned short Ahi[128 * 32];
    __shared__ __align__(16) unsigned short Alo[128 * 32];
    __shared__ __align__(16) unsigned short Bhi[128 * 32];
    __shared__ __align__(16) unsigned short Blo[128 * 32];
    __shared__ unsigned long long Red[128][2];

    const int t    = threadIdx.x;
    const int w    = t >> 6;
    const int lane = t & 63;
    const int quad = lane >> 4;
    const int l16  = lane & 15;
    const int wm   = w & 1, wn = w >> 1;
    const int rowBase = blockIdx.x * 128;
    const int colBase = blockIdx.y * 128;

    f32x4 acc[4][4];
    #pragma unroll
    for (int i = 0; i < 4; ++i)
        #pragma unroll
        for (int j = 0; j < 4; ++j)
            acc[i][j] = (f32x4)(0.0f);

    // staging: thread t loads 8 ushorts (16B): tile row mr (+64 for 2nd inst), k-quad kq
    const int mr = t >> 2;
    const int kq = (t & 3) * 8;
    const size_t gxa = (size_t)(rowBase + mr) * DIMK + kq;
    const size_t gxb = gxa + (size_t)64 * DIMK;
    const size_t gca = (size_t)(colBase + mr) * DIMK + kq;
    const size_t gcb = gca + (size_t)64 * DIMK;
    const int l0 = w * 512;          // wave-uniform LDS base (elements), inst0
    const int l1 = 2048 + w * 512;   // inst1 (+4096 B)

    for (int k0 = 0; k0 < DIMK; k0 += 32) {
        load_lds16(Xhi + gxa + k0, &Ahi[l0]);
        load_lds16(Xhi + gxb + k0, &Ahi[l1]);
        load_lds16(Xlo + gxa + k0, &Alo[l0]);
        load_lds16(Xlo + gxb + k0, &Alo[l1]);
        load_lds16(Chi + gca + k0, &Bhi[l0]);
        load_lds16(Chi + gcb + k0, &Bhi[l1]);
        load_lds16(Clo + gca + k0, &Blo[l0]);
        load_lds16(Clo + gcb + k0, &Blo[l1]);
        __syncthreads();

        s16x8 ah[4], al[4], bh[4], bl[4];
        #pragma unroll
        for (int i = 0; i < 4; ++i) {
            const int m = wm * 64 + i * 16 + l16;
            const int off = m * 32 + quad * 8;
            ah[i] = *(const s16x8*)&Ahi[off];
            al[i] = *(const s16x8*)&Alo[off];
        }
        #pragma unroll
        for (int j = 0; j < 4; ++j) {
            const int n = wn * 64 + j * 16 + l16;
            const int off = n * 32 + quad * 8;
            bh[j] = *(const s16x8*)&Bhi[off];
            bl[j] = *(const s16x8*)&Blo[off];
        }
        #pragma unroll
        for (int i = 0; i < 4; ++i)
            #pragma unroll
            for (int j = 0; j < 4; ++j) {
                acc[i][j] = __builtin_amdgcn_mfma_f32_16x16x32_bf16(ah[i], bh[j], acc[i][j], 0, 0, 0);
                acc[i][j] = __builtin_amdgcn_mfma_f32_16x16x32_bf16(ah[i], bl[j], acc[i][j], 0, 0, 0);
                acc[i][j] = __builtin_amdgcn_mfma_f32_16x16x32_bf16(al[i], bh[j], acc[i][j], 0, 0, 0);
            }
        __syncthreads();
    }

    // epilogue: d2 = norm[col] - 2*dot; per-row argmin
    // C/D layout (m89-verified): col = j*16 + l16, row = i*16 + quad*4 + reg
    float nrm[4];
    #pragma unroll
    for (int j = 0; j < 4; ++j)
        nrm[j] = Norms[colBase + wn * 64 + j * 16 + l16];

    #pragma unroll
    for (int i = 0; i < 4; ++i) {
        #pragma unroll
        for (int r = 0; r < 4; ++r) {
            unsigned long long m = ~0ull;
            #pragma unroll
            for (int j = 0; j < 4; ++j) {
                const unsigned col = colBase + wn * 64 + j * 16 + l16;
                const float d2 = fmaf(-2.0f, acc[i][j][r], nrm[j]);
                m = u64min(m, packMin(d2, col));
            }
            #pragma unroll
            for (int mask = 1; mask < 16; mask <<= 1) {
                unsigned long long o = (unsigned long long)__shfl_xor((long long)m, mask, 64);
                m = u64min(m, o);
            }
            if (l16 == 0) {
                const int rl = wm * 64 + i * 16 + quad * 4 + r;
                Red[rl][wn] = m;
            }
        }
    }
    __syncthreads();
    if (t < 128) {
        unsigned long long m = u64min(Red[t][0], Red[t][1]);
        atomicMin(&Packed[rowBase + t], m);
    }
}

// ---------------- gather + commit loss ----------------
__global__ __launch_bounds__(128) void gather_loss(const float* __restrict__ X,
                                                   const float* __restrict__ Codes,
                                                   const unsigned long long* __restrict__ Packed,
                                                   float* __restrict__ outQ,
                                                   float* __restrict__ outIdx,
                                                   float* __restrict__ lossAccum) {
    const int row = blockIdx.x;
    const int t = threadIdx.x;
    const unsigned idx = (unsigned)(Packed[row] & 0xFFFFFFFFull);
    float4 q  = *(const float4*)(Codes + (size_t)idx * DIMK + (t << 2));
    float4 xv = *(const float4*)(X + (size_t)row * DIMK + (t << 2));
    *(float4*)(outQ + (size_t)row * DIMK + (t << 2)) = q;
    float dx = xv.x - q.x, dy = xv.y - q.y, dz = xv.z - q.z, dw = xv.w - q.w;
    float s = dx * dx + dy * dy + dz * dz + dw * dw;
    #pragma unroll
    for (int off = 32; off > 0; off >>= 1) s += __shfl_down(s, off);
    __shared__ float red[2];
    if ((t & 63) == 0) red[t >> 6] = s;
    __syncthreads();
    if (t == 0) {
        atomicAdd(lossAccum, red[0] + red[1]);
        outIdx[row] = (float)idx;
    }
}

__global__ void finalize_loss(const float* __restrict__ lossAccum, float* __restrict__ outLoss) {
    *outLoss = *lossAccum * (1.0f / (float)((size_t)MROWS * DIMK));
}

extern "C" void kernel_launch(void* const* d_in, const int* in_sizes, int n_in,
                              void* d_out, int out_size, void* d_ws, size_t ws_size,
                              hipStream_t stream) {
    const float* x  = (const float*)d_in[0];   // [16384, 512]
    const float* cb = (const float*)d_in[1];   // [8192, 512]
    const float* W  = (const float*)d_in[2];   // [512, 512]
    float* out = (float*)d_out;

    char* ws = (char*)d_ws;
    float* codes              = (float*)(ws + WS_CODES);
    unsigned short* xhi       = (unsigned short*)(ws + WS_XHI);
    unsigned short* xlo       = (unsigned short*)(ws + WS_XLO);
    unsigned short* chi       = (unsigned short*)(ws + WS_CHI);
    unsigned short* clo       = (unsigned short*)(ws + WS_CLO);
    float* norms              = (float*)(ws + WS_NORMS);
    unsigned long long* packed= (unsigned long long*)(ws + WS_PACKED);
    float* loss               = (float*)(ws + WS_LOSS);

    hipMemsetAsync(packed, 0xFF, (size_t)MROWS * 8, stream);
    hipMemsetAsync(loss, 0, 4, stream);

    // x -> bf16 hi/lo
    split_bf16<<<(MROWS * DIMK / 4 + 255) / 256, 256, 0, stream>>>(x, xhi, xlo, MROWS * DIMK / 4);
    // codes = codebook @ W^T (f32)
    codes_gemm<<<dim3(CBN / BM, DIMK / BN), 256, 0, stream>>>(cb, W, codes);
    // codes -> bf16 hi/lo
    split_bf16<<<(CBN * DIMK / 4 + 255) / 256, 256, 0, stream>>>(codes, chi, clo, CBN * DIMK / 4);
    // ||codes||^2
    norms_kernel<<<CBN, 128, 0, stream>>>(codes, norms);
    // fused MFMA distance + argmin
    d2_argmin_mfma<<<dim3(MROWS / 128, CBN / 128), 256, 0, stream>>>(xhi, xlo, chi, clo, norms, packed);
    // gather + loss
    gather_loss<<<MROWS, 128, 0, stream>>>(x, codes, packed, out, out + (size_t)MROWS * DIMK, loss);
    finalize_loss<<<1, 1, 0, stream>>>(loss, out + (size_t)MROWS * DIMK + MROWS);
}

// Round 3
// 585.374 us; speedup vs baseline: 3.7407x; 1.3340x over previous
//
#include <hip/hip_runtime.h>

// SimVQ: x[8,2048,512] f32, codebook[8192,512] f32, W[512,512] f32
// out = concat(quantized[16384*512], indices[16384] (as f32), commit_loss[1])
// Rotation-trick forward value == gathered code exactly, so quantized = codes[idx].
//
// Round 3: keep MFMA d2 (3-pass bf16 hi/lo, 961 TF effective). Deflate the
// auxiliary chain: fuse codes split+norms into codes_gemm epilogue; replace the
// 16384 same-address atomicAdd loss with partials + deterministic reduce.

#define DIMK  512
#define CBN   8192
#define MROWS 16384

// ws layout (bytes)
#define WS_CODES   0UL                       // 8192*512*4  = 16,777,216
#define WS_XHI     16777216UL                // 16384*512*2 = 16,777,216
#define WS_XLO     33554432UL
#define WS_CHI     50331648UL                // 8192*512*2  = 8,388,608
#define WS_CLO     58720256UL
#define WS_NORMS   67108864UL                // 8192*4
#define WS_PACKED  67141632UL                // 16384*8
#define WS_LOSSP   67272704UL                // 16384*4 loss partials

typedef short s16x8 __attribute__((ext_vector_type(8)));
typedef float f32x4 __attribute__((ext_vector_type(4)));

__device__ __forceinline__ unsigned short f2bf(float f) {
    unsigned u = __float_as_uint(f);
    unsigned r = u + 0x7FFFu + ((u >> 16) & 1u);   // RTNE
    return (unsigned short)(r >> 16);
}
__device__ __forceinline__ float bf2f(unsigned short h) {
    return __uint_as_float(((unsigned)h) << 16);
}

__device__ __forceinline__ unsigned long long packMin(float f, unsigned idx) {
    unsigned u = __float_as_uint(f);
    u = (u & 0x80000000u) ? ~u : (u | 0x80000000u);   // monotone float->uint
    return (((unsigned long long)u) << 32) | (unsigned long long)idx;
}
__device__ __forceinline__ unsigned long long u64min(unsigned long long a, unsigned long long b) {
    return (b < a) ? b : a;
}

__device__ __forceinline__ void load_lds16(const void* g, void* l) {
    __builtin_amdgcn_global_load_lds((const __attribute__((address_space(1))) void*)g,
                                     (__attribute__((address_space(3))) void*)l,
                                     16, 0, 0);
}

// ---------------- split f32 -> bf16 hi + bf16 lo (x only) ----------------
__global__ __launch_bounds__(256) void split_bf16(const float* __restrict__ in,
                                                  unsigned short* __restrict__ hi,
                                                  unsigned short* __restrict__ lo,
                                                  int n4) {
    int i = blockIdx.x * 256 + threadIdx.x;
    if (i >= n4) return;
    float4 v = ((const float4*)in)[i];
    ushort4 h, l;
    h.x = f2bf(v.x); l.x = f2bf(v.x - bf2f(h.x));
    h.y = f2bf(v.y); l.y = f2bf(v.y - bf2f(h.y));
    h.z = f2bf(v.z); l.z = f2bf(v.z - bf2f(h.z));
    h.w = f2bf(v.w); l.w = f2bf(v.w - bf2f(h.w));
    ((ushort4*)hi)[i] = h;
    ((ushort4*)lo)[i] = l;
}

// ------- codes = codebook @ W^T (f32) fused with bf16 split + norm partials -------
#define BM 64
#define BN 64
#define BK 16
__global__ __launch_bounds__(256) void codes_gemm_fused(const float* __restrict__ A,
                                                        const float* __restrict__ B,
                                                        float* __restrict__ C,
                                                        unsigned short* __restrict__ Chi,
                                                        unsigned short* __restrict__ Clo,
                                                        float* __restrict__ Norms) {
    __shared__ float As[BK][BM];
    __shared__ float Bs[BK][BN];
    const int t  = threadIdx.x;
    const int tx = t & 15, ty = t >> 4;
    const int rowBase = blockIdx.x * BM;
    const int colBase = blockIdx.y * BN;
    const int lr = t >> 2;
    const int lk = (t & 3) << 2;

    float4 c0 = make_float4(0,0,0,0), c1 = c0, c2 = c0, c3 = c0;
    const float* Ap = A + (size_t)(rowBase + lr) * DIMK + lk;
    const float* Bp = B + (size_t)(colBase + lr) * DIMK + lk;

    for (int k0 = 0; k0 < DIMK; k0 += BK) {
        float4 av = *(const float4*)(Ap + k0);
        float4 bv = *(const float4*)(Bp + k0);
        As[lk + 0][lr] = av.x; As[lk + 1][lr] = av.y; As[lk + 2][lr] = av.z; As[lk + 3][lr] = av.w;
        Bs[lk + 0][lr] = bv.x; Bs[lk + 1][lr] = bv.y; Bs[lk + 2][lr] = bv.z; Bs[lk + 3][lr] = bv.w;
        __syncthreads();
        #pragma unroll
        for (int k = 0; k < BK; ++k) {
            float4 a = *(const float4*)&As[k][ty << 2];
            float4 b = *(const float4*)&Bs[k][tx << 2];
            c0.x = fmaf(a.x, b.x, c0.x); c0.y = fmaf(a.x, b.y, c0.y); c0.z = fmaf(a.x, b.z, c0.z); c0.w = fmaf(a.x, b.w, c0.w);
            c1.x = fmaf(a.y, b.x, c1.x); c1.y = fmaf(a.y, b.y, c1.y); c1.z = fmaf(a.y, b.z, c1.z); c1.w = fmaf(a.y, b.w, c1.w);
            c2.x = fmaf(a.z, b.x, c2.x); c2.y = fmaf(a.z, b.y, c2.y); c2.z = fmaf(a.z, b.z, c2.z); c2.w = fmaf(a.z, b.w, c2.w);
            c3.x = fmaf(a.w, b.x, c3.x); c3.y = fmaf(a.w, b.y, c3.y); c3.z = fmaf(a.w, b.z, c3.z); c3.w = fmaf(a.w, b.w, c3.w);
        }
        __syncthreads();
    }
    const int r0 = rowBase + (ty << 2);
    const int cc = colBase + (tx << 2);
    #pragma unroll
    for (int i = 0; i < 4; ++i) {
        float4 c = (i == 0) ? c0 : (i == 1) ? c1 : (i == 2) ? c2 : c3;
        const size_t off = (size_t)(r0 + i) * DIMK + cc;
        *(float4*)(C + off) = c;
        ushort4 h, l;
        h.x = f2bf(c.x); l.x = f2bf(c.x - bf2f(h.x));
        h.y = f2bf(c.y); l.y = f2bf(c.y - bf2f(h.y));
        h.z = f2bf(c.z); l.z = f2bf(c.z - bf2f(h.z));
        h.w = f2bf(c.w); l.w = f2bf(c.w - bf2f(h.w));
        *(ushort4*)(Chi + off) = h;
        *(ushort4*)(Clo + off) = l;
        // norm partial over this block's 64 cols: reduce across the 16 tx lanes
        float s = c.x * c.x + c.y * c.y + c.z * c.z + c.w * c.w;
        s += __shfl_xor(s, 1);
        s += __shfl_xor(s, 2);
        s += __shfl_xor(s, 4);
        s += __shfl_xor(s, 8);
        if (tx == 0) atomicAdd(&Norms[r0 + i], s);
    }
}

// ---------------- fused distance GEMM (MFMA bf16 hi/lo) + argmin ----------------
// grid: (MROWS/128, CBN/128), 256 threads (4 waves, 2x2 of 64x64 each)
__global__ __launch_bounds__(256) void d2_argmin_mfma(
        const unsigned short* __restrict__ Xhi, const unsigned short* __restrict__ Xlo,
        const unsigned short* __restrict__ Chi, const unsigned short* __restrict__ Clo,
        const float* __restrict__ Norms, unsigned long long* __restrict__ Packed) {
    __shared__ __align__(16) unsigned short Ahi[128 * 32];
    __shared__ __align__(16) unsigned short Alo[128 * 32];
    __shared__ __align__(16) unsigned short Bhi[128 * 32];
    __shared__ __align__(16) unsigned short Blo[128 * 32];
    __shared__ unsigned long long Red[128][2];

    const int t    = threadIdx.x;
    const int w    = t >> 6;
    const int lane = t & 63;
    const int quad = lane >> 4;
    const int l16  = lane & 15;
    const int wm   = w & 1, wn = w >> 1;
    const int rowBase = blockIdx.x * 128;
    const int colBase = blockIdx.y * 128;

    f32x4 acc[4][4];
    #pragma unroll
    for (int i = 0; i < 4; ++i)
        #pragma unroll
        for (int j = 0; j < 4; ++j)
            acc[i][j] = (f32x4)(0.0f);

    const int mr = t >> 2;
    const int kq = (t & 3) * 8;
    const size_t gxa = (size_t)(rowBase + mr) * DIMK + kq;
    const size_t gxb = gxa + (size_t)64 * DIMK;
    const size_t gca = (size_t)(colBase + mr) * DIMK + kq;
    const size_t gcb = gca + (size_t)64 * DIMK;
    const int l0 = w * 512;
    const int l1 = 2048 + w * 512;

    for (int k0 = 0; k0 < DIMK; k0 += 32) {
        load_lds16(Xhi + gxa + k0, &Ahi[l0]);
        load_lds16(Xhi + gxb + k0, &Ahi[l1]);
        load_lds16(Xlo + gxa + k0, &Alo[l0]);
        load_lds16(Xlo + gxb + k0, &Alo[l1]);
        load_lds16(Chi + gca + k0, &Bhi[l0]);
        load_lds16(Chi + gcb + k0, &Bhi[l1]);
        load_lds16(Clo + gca + k0, &Blo[l0]);
        load_lds16(Clo + gcb + k0, &Blo[l1]);
        __syncthreads();

        s16x8 ah[4], al[4], bh[4], bl[4];
        #pragma unroll
        for (int i = 0; i < 4; ++i) {
            const int m = wm * 64 + i * 16 + l16;
            const int off = m * 32 + quad * 8;
            ah[i] = *(const s16x8*)&Ahi[off];
            al[i] = *(const s16x8*)&Alo[off];
        }
        #pragma unroll
        for (int j = 0; j < 4; ++j) {
            const int n = wn * 64 + j * 16 + l16;
            const int off = n * 32 + quad * 8;
            bh[j] = *(const s16x8*)&Bhi[off];
            bl[j] = *(const s16x8*)&Blo[off];
        }
        #pragma unroll
        for (int i = 0; i < 4; ++i)
            #pragma unroll
            for (int j = 0; j < 4; ++j) {
                acc[i][j] = __builtin_amdgcn_mfma_f32_16x16x32_bf16(ah[i], bh[j], acc[i][j], 0, 0, 0);
                acc[i][j] = __builtin_amdgcn_mfma_f32_16x16x32_bf16(ah[i], bl[j], acc[i][j], 0, 0, 0);
                acc[i][j] = __builtin_amdgcn_mfma_f32_16x16x32_bf16(al[i], bh[j], acc[i][j], 0, 0, 0);
            }
        __syncthreads();
    }

    // epilogue: d2 = norm[col] - 2*dot; per-row argmin
    // C/D layout (m89-verified): col = j*16 + l16, row = i*16 + quad*4 + reg
    float nrm[4];
    #pragma unroll
    for (int j = 0; j < 4; ++j)
        nrm[j] = Norms[colBase + wn * 64 + j * 16 + l16];

    #pragma unroll
    for (int i = 0; i < 4; ++i) {
        #pragma unroll
        for (int r = 0; r < 4; ++r) {
            unsigned long long m = ~0ull;
            #pragma unroll
            for (int j = 0; j < 4; ++j) {
                const unsigned col = colBase + wn * 64 + j * 16 + l16;
                const float d2 = fmaf(-2.0f, acc[i][j][r], nrm[j]);
                m = u64min(m, packMin(d2, col));
            }
            #pragma unroll
            for (int mask = 1; mask < 16; mask <<= 1) {
                unsigned long long o = (unsigned long long)__shfl_xor((long long)m, mask, 64);
                m = u64min(m, o);
            }
            if (l16 == 0) {
                const int rl = wm * 64 + i * 16 + quad * 4 + r;
                Red[rl][wn] = m;
            }
        }
    }
    __syncthreads();
    if (t < 128) {
        unsigned long long m = u64min(Red[t][0], Red[t][1]);
        atomicMin(&Packed[rowBase + t], m);
    }
}

// ---------------- gather + commit loss (per-block partials, no contention) ----------------
__global__ __launch_bounds__(128) void gather_loss(const float* __restrict__ X,
                                                   const float* __restrict__ Codes,
                                                   const unsigned long long* __restrict__ Packed,
                                                   float* __restrict__ outQ,
                                                   float* __restrict__ outIdx,
                                                   float* __restrict__ lossPartials) {
    const int row = blockIdx.x;
    const int t = threadIdx.x;
    const unsigned idx = (unsigned)(Packed[row] & 0xFFFFFFFFull);
    float4 q  = *(const float4*)(Codes + (size_t)idx * DIMK + (t << 2));
    float4 xv = *(const float4*)(X + (size_t)row * DIMK + (t << 2));
    *(float4*)(outQ + (size_t)row * DIMK + (t << 2)) = q;
    float dx = xv.x - q.x, dy = xv.y - q.y, dz = xv.z - q.z, dw = xv.w - q.w;
    float s = dx * dx + dy * dy + dz * dz + dw * dw;
    #pragma unroll
    for (int off = 32; off > 0; off >>= 1) s += __shfl_down(s, off);
    __shared__ float red[2];
    if ((t & 63) == 0) red[t >> 6] = s;
    __syncthreads();
    if (t == 0) {
        lossPartials[row] = red[0] + red[1];
        outIdx[row] = (float)idx;
    }
}

// deterministic tree-reduce of 16384 partials
__global__ __launch_bounds__(256) void finalize_loss(const float* __restrict__ lossPartials,
                                                     float* __restrict__ outLoss) {
    const int t = threadIdx.x;
    float s = 0.0f;
    for (int i = t; i < MROWS; i += 256) s += lossPartials[i];
    #pragma unroll
    for (int off = 32; off > 0; off >>= 1) s += __shfl_down(s, off);
    __shared__ float red[4];
    if ((t & 63) == 0) red[t >> 6] = s;
    __syncthreads();
    if (t == 0)
        *outLoss = (red[0] + red[1] + red[2] + red[3]) * (1.0f / (float)((size_t)MROWS * DIMK));
}

extern "C" void kernel_launch(void* const* d_in, const int* in_sizes, int n_in,
                              void* d_out, int out_size, void* d_ws, size_t ws_size,
                              hipStream_t stream) {
    const float* x  = (const float*)d_in[0];   // [16384, 512]
    const float* cb = (const float*)d_in[1];   // [8192, 512]
    const float* W  = (const float*)d_in[2];   // [512, 512]
    float* out = (float*)d_out;

    char* ws = (char*)d_ws;
    float* codes               = (float*)(ws + WS_CODES);
    unsigned short* xhi        = (unsigned short*)(ws + WS_XHI);
    unsigned short* xlo        = (unsigned short*)(ws + WS_XLO);
    unsigned short* chi        = (unsigned short*)(ws + WS_CHI);
    unsigned short* clo        = (unsigned short*)(ws + WS_CLO);
    float* norms               = (float*)(ws + WS_NORMS);
    unsigned long long* packed = (unsigned long long*)(ws + WS_PACKED);
    float* lossP               = (float*)(ws + WS_LOSSP);

    hipMemsetAsync(packed, 0xFF, (size_t)MROWS * 8, stream);
    hipMemsetAsync(norms, 0, CBN * 4, stream);

    // x -> bf16 hi/lo
    split_bf16<<<(MROWS * DIMK / 4 + 255) / 256, 256, 0, stream>>>(x, xhi, xlo, MROWS * DIMK / 4);
    // codes = codebook @ W^T (f32) + bf16 split + norms, fused
    codes_gemm_fused<<<dim3(CBN / BM, DIMK / BN), 256, 0, stream>>>(cb, W, codes, chi, clo, norms);
    // fused MFMA distance + argmin
    d2_argmin_mfma<<<dim3(MROWS / 128, CBN / 128), 256, 0, stream>>>(xhi, xlo, chi, clo, norms, packed);
    // gather + loss partials
    gather_loss<<<MROWS, 128, 0, stream>>>(x, codes, packed, out, out + (size_t)MROWS * DIMK, lossP);
    finalize_loss<<<1, 256, 0, stream>>>(lossP, out + (size_t)MROWS * DIMK + MROWS);
}

// Round 4
// 422.513 us; speedup vs baseline: 5.1826x; 1.3855x over previous
//
#include <hip/hip_runtime.h>

// SimVQ: x[8,2048,512] f32, codebook[8192,512] f32, W[512,512] f32
// out = concat(quantized[16384*512], indices[16384] (as f32), commit_loss[1])
// Rotation-trick forward value == gathered code exactly, so quantized = codes[idx].
//
// Round 4: approximate-then-refine argmin.
//   - d2 approx: 1-pass bf16(hi) MFMA (137 GF, was 412 GF for 3-pass)
//   - per-block top-2 candidates per row -> deterministic global array
//   - refine: exact f32 d2 on candidates within margin DELTA, fused with
//     gather + commit-loss partial.

#define DIMK  512
#define CBN   8192
#define MROWS 16384

// ws layout (bytes)
#define WS_CODES   0UL          // 8192*512*4   = 16,777,216
#define WS_XHI     16777216UL   // 16384*512*2  = 16,777,216
#define WS_CHI     33554432UL   // 8192*512*2   =  8,388,608
#define WS_NORMS   41943040UL   // 8192*4
#define WS_CAND    41975808UL   // 16384*64*2*8 = 16,777,216
#define WS_LOSSP   58753024UL   // 16384*4

#define DELTA 0.125f            // candidate margin: ~2x 9-sigma of hi-only d2 error

typedef short s16x8 __attribute__((ext_vector_type(8)));
typedef float f32x4 __attribute__((ext_vector_type(4)));

__device__ __forceinline__ unsigned short f2bf(float f) {
    unsigned u = __float_as_uint(f);
    unsigned r = u + 0x7FFFu + ((u >> 16) & 1u);   // RTNE
    return (unsigned short)(r >> 16);
}
__device__ __forceinline__ float bf2f(unsigned short h) {
    return __uint_as_float(((unsigned)h) << 16);
}

__device__ __forceinline__ unsigned long long packMin(float f, unsigned idx) {
    unsigned u = __float_as_uint(f);
    u = (u & 0x80000000u) ? ~u : (u | 0x80000000u);   // monotone float->uint
    return (((unsigned long long)u) << 32) | (unsigned long long)idx;
}
__device__ __forceinline__ float unpackKey(unsigned k) {
    unsigned u = (k & 0x80000000u) ? (k & 0x7FFFFFFFu) : ~k;
    return __uint_as_float(u);
}
__device__ __forceinline__ unsigned long long u64min(unsigned long long a, unsigned long long b) {
    return (b < a) ? b : a;
}
__device__ __forceinline__ unsigned long long u64max(unsigned long long a, unsigned long long b) {
    return (b > a) ? b : a;
}

__device__ __forceinline__ void load_lds16(const void* g, void* l) {
    __builtin_amdgcn_global_load_lds((const __attribute__((address_space(1))) void*)g,
                                     (__attribute__((address_space(3))) void*)l,
                                     16, 0, 0);
}

// ---------------- x -> bf16 hi ----------------
__global__ __launch_bounds__(256) void split_hi(const float* __restrict__ in,
                                                unsigned short* __restrict__ hi,
                                                int n4) {
    int i = blockIdx.x * 256 + threadIdx.x;
    if (i >= n4) return;
    float4 v = ((const float4*)in)[i];
    ushort4 h;
    h.x = f2bf(v.x); h.y = f2bf(v.y); h.z = f2bf(v.z); h.w = f2bf(v.w);
    ((ushort4*)hi)[i] = h;
}

// ------- codes = codebook @ W^T (f32) fused with bf16-hi + norm partials -------
#define BM 64
#define BN 64
#define BK 16
__global__ __launch_bounds__(256) void codes_gemm_fused(const float* __restrict__ A,
                                                        const float* __restrict__ B,
                                                        float* __restrict__ C,
                                                        unsigned short* __restrict__ Chi,
                                                        float* __restrict__ Norms) {
    __shared__ float As[BK][BM];
    __shared__ float Bs[BK][BN];
    const int t  = threadIdx.x;
    const int tx = t & 15, ty = t >> 4;
    const int rowBase = blockIdx.x * BM;
    const int colBase = blockIdx.y * BN;
    const int lr = t >> 2;
    const int lk = (t & 3) << 2;

    float4 c0 = make_float4(0,0,0,0), c1 = c0, c2 = c0, c3 = c0;
    const float* Ap = A + (size_t)(rowBase + lr) * DIMK + lk;
    const float* Bp = B + (size_t)(colBase + lr) * DIMK + lk;

    for (int k0 = 0; k0 < DIMK; k0 += BK) {
        float4 av = *(const float4*)(Ap + k0);
        float4 bv = *(const float4*)(Bp + k0);
        As[lk + 0][lr] = av.x; As[lk + 1][lr] = av.y; As[lk + 2][lr] = av.z; As[lk + 3][lr] = av.w;
        Bs[lk + 0][lr] = bv.x; Bs[lk + 1][lr] = bv.y; Bs[lk + 2][lr] = bv.z; Bs[lk + 3][lr] = bv.w;
        __syncthreads();
        #pragma unroll
        for (int k = 0; k < BK; ++k) {
            float4 a = *(const float4*)&As[k][ty << 2];
            float4 b = *(const float4*)&Bs[k][tx << 2];
            c0.x = fmaf(a.x, b.x, c0.x); c0.y = fmaf(a.x, b.y, c0.y); c0.z = fmaf(a.x, b.z, c0.z); c0.w = fmaf(a.x, b.w, c0.w);
            c1.x = fmaf(a.y, b.x, c1.x); c1.y = fmaf(a.y, b.y, c1.y); c1.z = fmaf(a.y, b.z, c1.z); c1.w = fmaf(a.y, b.w, c1.w);
            c2.x = fmaf(a.z, b.x, c2.x); c2.y = fmaf(a.z, b.y, c2.y); c2.z = fmaf(a.z, b.z, c2.z); c2.w = fmaf(a.z, b.w, c2.w);
            c3.x = fmaf(a.w, b.x, c3.x); c3.y = fmaf(a.w, b.y, c3.y); c3.z = fmaf(a.w, b.z, c3.z); c3.w = fmaf(a.w, b.w, c3.w);
        }
        __syncthreads();
    }
    const int r0 = rowBase + (ty << 2);
    const int cc = colBase + (tx << 2);
    #pragma unroll
    for (int i = 0; i < 4; ++i) {
        float4 c = (i == 0) ? c0 : (i == 1) ? c1 : (i == 2) ? c2 : c3;
        const size_t off = (size_t)(r0 + i) * DIMK + cc;
        *(float4*)(C + off) = c;
        ushort4 h;
        h.x = f2bf(c.x); h.y = f2bf(c.y); h.z = f2bf(c.z); h.w = f2bf(c.w);
        *(ushort4*)(Chi + off) = h;
        float s = c.x * c.x + c.y * c.y + c.z * c.z + c.w * c.w;
        s += __shfl_xor(s, 1);
        s += __shfl_xor(s, 2);
        s += __shfl_xor(s, 4);
        s += __shfl_xor(s, 8);
        if (tx == 0) atomicAdd(&Norms[r0 + i], s);
    }
}

// ---------- approx distance GEMM (MFMA bf16 hi only) + per-block top-2 ----------
// grid: (MROWS/128, CBN/128), 256 threads (4 waves, 2x2 of 64x64 each)
__global__ __launch_bounds__(256) void d2_approx_mfma(
        const unsigned short* __restrict__ Xhi,
        const unsigned short* __restrict__ Chi,
        const float* __restrict__ Norms,
        unsigned long long* __restrict__ Cand) {
    __shared__ __align__(16) unsigned short Ahi[128 * 32];
    __shared__ __align__(16) unsigned short Bhi[128 * 32];
    __shared__ unsigned long long Red[128][2][2];

    const int t    = threadIdx.x;
    const int w    = t >> 6;
    const int lane = t & 63;
    const int quad = lane >> 4;
    const int l16  = lane & 15;
    const int wm   = w & 1, wn = w >> 1;
    const int rowBase = blockIdx.x * 128;
    const int colBase = blockIdx.y * 128;

    f32x4 acc[4][4];
    #pragma unroll
    for (int i = 0; i < 4; ++i)
        #pragma unroll
        for (int j = 0; j < 4; ++j)
            acc[i][j] = (f32x4)(0.0f);

    const int mr = t >> 2;
    const int kq = (t & 3) * 8;
    const size_t gxa = (size_t)(rowBase + mr) * DIMK + kq;
    const size_t gxb = gxa + (size_t)64 * DIMK;
    const size_t gca = (size_t)(colBase + mr) * DIMK + kq;
    const size_t gcb = gca + (size_t)64 * DIMK;
    const int l0 = w * 512;
    const int l1 = 2048 + w * 512;

    for (int k0 = 0; k0 < DIMK; k0 += 32) {
        load_lds16(Xhi + gxa + k0, &Ahi[l0]);
        load_lds16(Xhi + gxb + k0, &Ahi[l1]);
        load_lds16(Chi + gca + k0, &Bhi[l0]);
        load_lds16(Chi + gcb + k0, &Bhi[l1]);
        __syncthreads();

        s16x8 ah[4], bh[4];
        #pragma unroll
        for (int i = 0; i < 4; ++i) {
            const int m = wm * 64 + i * 16 + l16;
            ah[i] = *(const s16x8*)&Ahi[m * 32 + quad * 8];
        }
        #pragma unroll
        for (int j = 0; j < 4; ++j) {
            const int n = wn * 64 + j * 16 + l16;
            bh[j] = *(const s16x8*)&Bhi[n * 32 + quad * 8];
        }
        #pragma unroll
        for (int i = 0; i < 4; ++i)
            #pragma unroll
            for (int j = 0; j < 4; ++j)
                acc[i][j] = __builtin_amdgcn_mfma_f32_16x16x32_bf16(ah[i], bh[j], acc[i][j], 0, 0, 0);
        __syncthreads();
    }

    // epilogue: d2 = norm - 2*dot; per-row top-2 over this block's 128 cols.
    // C/D layout (m89-verified): col = j*16 + l16, row = i*16 + quad*4 + reg
    float nrm[4];
    #pragma unroll
    for (int j = 0; j < 4; ++j)
        nrm[j] = Norms[colBase + wn * 64 + j * 16 + l16];

    #pragma unroll
    for (int i = 0; i < 4; ++i) {
        #pragma unroll
        for (int r = 0; r < 4; ++r) {
            unsigned long long m1 = ~0ull, m2 = ~0ull;
            #pragma unroll
            for (int j = 0; j < 4; ++j) {
                const unsigned col = colBase + wn * 64 + j * 16 + l16;
                const float d2 = fmaf(-2.0f, acc[i][j][r], nrm[j]);
                unsigned long long v = packMin(d2, col);
                if (v < m1) { m2 = m1; m1 = v; } else { m2 = u64min(m2, v); }
            }
            // top-2 butterfly across the 16 lanes holding this row's cols
            #pragma unroll
            for (int mask = 1; mask < 16; mask <<= 1) {
                unsigned long long p1 = (unsigned long long)__shfl_xor((long long)m1, mask, 64);
                unsigned long long p2 = (unsigned long long)__shfl_xor((long long)m2, mask, 64);
                unsigned long long n1 = u64min(m1, p1);
                unsigned long long n2 = u64min(u64max(m1, p1), u64min(m2, p2));
                m1 = n1; m2 = n2;
            }
            if (l16 == 0) {
                const int rl = wm * 64 + i * 16 + quad * 4 + r;
                Red[rl][wn][0] = m1;
                Red[rl][wn][1] = m2;
            }
        }
    }
    __syncthreads();
    if (t < 128) {
        unsigned long long a1 = Red[t][0][0], a2 = Red[t][0][1];
        unsigned long long b1 = Red[t][1][0], b2 = Red[t][1][1];
        unsigned long long c1 = u64min(a1, b1);
        unsigned long long c2 = u64min(u64max(a1, b1), u64min(a2, b2));
        const size_t base = ((size_t)(rowBase + t) * 64 + blockIdx.y) * 2;
        Cand[base]     = c1;
        Cand[base + 1] = c2;
    }
}

// ---------- refine candidates exactly (f32) + gather + loss partial ----------
// one wave per row; 4 waves / block
__global__ __launch_bounds__(256) void refine_gather(
        const float* __restrict__ X, const float* __restrict__ Codes,
        const float* __restrict__ Norms, const unsigned long long* __restrict__ Cand,
        float* __restrict__ outQ, float* __restrict__ outIdx,
        float* __restrict__ lossP) {
    const int t    = threadIdx.x;
    const int w    = t >> 6;
    const int lane = t & 63;
    const int row  = blockIdx.x * 4 + w;

    const unsigned long long* cb = Cand + (size_t)row * 128;
    unsigned long long e0 = cb[lane * 2];
    unsigned long long e1 = cb[lane * 2 + 1];
    unsigned long long m = u64min(e0, e1);
    #pragma unroll
    for (int mask = 1; mask < 64; mask <<= 1)
        m = u64min(m, (unsigned long long)__shfl_xor((long long)m, mask, 64));

    const float thr = unpackKey((unsigned)(m >> 32)) + DELTA;
    unsigned long long mask0 = __ballot(unpackKey((unsigned)(e0 >> 32)) <= thr);
    unsigned long long mask1 = __ballot(unpackKey((unsigned)(e1 >> 32)) <= thr);

    const float4 xa = *(const float4*)(X + (size_t)row * DIMK + lane * 8);
    const float4 xb = *(const float4*)(X + (size_t)row * DIMK + lane * 8 + 4);

    float bestD = __builtin_inff();
    unsigned bestIdx = 0xFFFFFFFFu;

    #pragma unroll
    for (int s = 0; s < 2; ++s) {
        unsigned long long mk = s ? mask1 : mask0;
        unsigned long long ev = s ? e1 : e0;
        while (mk) {
            const int src = __ffsll(mk) - 1;
            mk &= mk - 1;
            const unsigned idx = (unsigned)(((unsigned long long)__shfl((long long)ev, src, 64)) & 0xFFFFFFFFull);
            const float4 ca = *(const float4*)(Codes + (size_t)idx * DIMK + lane * 8);
            const float4 cbv = *(const float4*)(Codes + (size_t)idx * DIMK + lane * 8 + 4);
            float s2 = xa.x * ca.x + xa.y * ca.y + xa.z * ca.z + xa.w * ca.w
                     + xb.x * cbv.x + xb.y * cbv.y + xb.z * cbv.z + xb.w * cbv.w;
            #pragma unroll
            for (int mm = 1; mm < 64; mm <<= 1) s2 += __shfl_xor(s2, mm, 64);
            const float d2 = fmaf(-2.0f, s2, Norms[idx]);
            if (d2 < bestD || (d2 == bestD && idx < bestIdx)) { bestD = d2; bestIdx = idx; }
        }
    }

    // gather quantized + loss partial
    const float4 qa = *(const float4*)(Codes + (size_t)bestIdx * DIMK + lane * 8);
    const float4 qb = *(const float4*)(Codes + (size_t)bestIdx * DIMK + lane * 8 + 4);
    *(float4*)(outQ + (size_t)row * DIMK + lane * 8) = qa;
    *(float4*)(outQ + (size_t)row * DIMK + lane * 8 + 4) = qb;
    float dx0 = xa.x - qa.x, dx1 = xa.y - qa.y, dx2 = xa.z - qa.z, dx3 = xa.w - qa.w;
    float dy0 = xb.x - qb.x, dy1 = xb.y - qb.y, dy2 = xb.z - qb.z, dy3 = xb.w - qb.w;
    float s = dx0 * dx0 + dx1 * dx1 + dx2 * dx2 + dx3 * dx3
            + dy0 * dy0 + dy1 * dy1 + dy2 * dy2 + dy3 * dy3;
    #pragma unroll
    for (int off = 32; off > 0; off >>= 1) s += __shfl_down(s, off);
    if (lane == 0) {
        lossP[row] = s;
        outIdx[row] = (float)bestIdx;
    }
}

// deterministic tree-reduce of 16384 partials
__global__ __launch_bounds__(256) void finalize_loss(const float* __restrict__ lossPartials,
                                                     float* __restrict__ outLoss) {
    const int t = threadIdx.x;
    float s = 0.0f;
    for (int i = t; i < MROWS; i += 256) s += lossPartials[i];
    #pragma unroll
    for (int off = 32; off > 0; off >>= 1) s += __shfl_down(s, off);
    __shared__ float red[4];
    if ((t & 63) == 0) red[t >> 6] = s;
    __syncthreads();
    if (t == 0)
        *outLoss = (red[0] + red[1] + red[2] + red[3]) * (1.0f / (float)((size_t)MROWS * DIMK));
}

extern "C" void kernel_launch(void* const* d_in, const int* in_sizes, int n_in,
                              void* d_out, int out_size, void* d_ws, size_t ws_size,
                              hipStream_t stream) {
    const float* x  = (const float*)d_in[0];   // [16384, 512]
    const float* cb = (const float*)d_in[1];   // [8192, 512]
    const float* W  = (const float*)d_in[2];   // [512, 512]
    float* out = (float*)d_out;

    char* ws = (char*)d_ws;
    float* codes               = (float*)(ws + WS_CODES);
    unsigned short* xhi        = (unsigned short*)(ws + WS_XHI);
    unsigned short* chi        = (unsigned short*)(ws + WS_CHI);
    float* norms               = (float*)(ws + WS_NORMS);
    unsigned long long* cand   = (unsigned long long*)(ws + WS_CAND);
    float* lossP               = (float*)(ws + WS_LOSSP);

    hipMemsetAsync(norms, 0, CBN * 4, stream);

    // x -> bf16 hi
    split_hi<<<(MROWS * DIMK / 4 + 255) / 256, 256, 0, stream>>>(x, xhi, MROWS * DIMK / 4);
    // codes = codebook @ W^T (f32) + bf16 hi + norms
    codes_gemm_fused<<<dim3(CBN / BM, DIMK / BN), 256, 0, stream>>>(cb, W, codes, chi, norms);
    // approx MFMA distance + per-block top-2 candidates
    d2_approx_mfma<<<dim3(MROWS / 128, CBN / 128), 256, 0, stream>>>(xhi, chi, norms, cand);
    // exact refine + gather + loss partials
    refine_gather<<<MROWS / 4, 256, 0, stream>>>(x, codes, norms, cand, out,
                                                 out + (size_t)MROWS * DIMK, lossP);
    finalize_loss<<<1, 256, 0, stream>>>(lossP, out + (size_t)MROWS * DIMK + MROWS);
}

// Round 5
// 390.207 us; speedup vs baseline: 5.6117x; 1.0828x over previous
//
#include <hip/hip_runtime.h>

// SimVQ: x[8,2048,512] f32, codebook[8192,512] f32, W[512,512] f32
// out = concat(quantized[16384*512], indices[16384] (as f32), commit_loss[1])
// Rotation-trick forward value == gathered code exactly, so quantized = codes[idx].
//
// Round 5: i8 MFMA distance pass (16x16x64, 2x bf16 rate, half staging bytes)
// + cheap f32-ballot candidate emission (replaces u64 top-2 butterflies).
// Candidates: per (row, 64-col subtile) up to 3 packed u32 slots (key19|col13),
// threshold = subtile min + DELTA. Refine filters by global min + DELTA, exact f32.

#define DIMK  512
#define CBN   8192
#define MROWS 16384

#define SX 24.0f               // x quant scale (clamp +-127 => +-5.29 sigma)
#define SC 500.0f              // codes quant scale (codes elem ~ N(0, 1/512))
#define INV_SS (1.0f / (SX * SC))
#define DELTA 0.3f             // 6 sigma of pairwise i8-quant d2 error (sigma~0.05)
#define DKEY  1231             // ceil(DELTA*4096) + quantization guard
#define NSLOT 3

// ws layout (bytes)
#define WS_CODES   0UL          // 8192*512*4        = 16,777,216
#define WS_XQ      16777216UL   // 16384*512         =  8,388,608
#define WS_CQ      25165824UL   // 8192*512          =  4,194,304
#define WS_NORMS   29360128UL   // 8192*4            =     32,768
#define WS_CAND    29392896UL   // 16384*128*3*4     = 25,165,824
#define WS_LOSSP   54558720UL   // 16384*4

typedef int   i32x4 __attribute__((ext_vector_type(4)));
typedef float f32x4 __attribute__((ext_vector_type(4)));

__device__ __forceinline__ void load_lds16(const void* g, void* l) {
    __builtin_amdgcn_global_load_lds((const __attribute__((address_space(1))) void*)g,
                                     (__attribute__((address_space(3))) void*)l,
                                     16, 0, 0);
}

__device__ __forceinline__ signed char q8(float v, float s) {
    return (signed char)__float2int_rn(fminf(fmaxf(v * s, -127.0f), 127.0f));
}

// pack (d2, col) -> u32 ordered key: key = (d2+16)*4096 in high 19 bits, col low 13
__device__ __forceinline__ unsigned packSlot(float d, unsigned col) {
    int k = (int)((d + 16.0f) * 4096.0f);
    k = k < 0 ? 0 : (k > 524287 ? 524287 : k);
    return ((unsigned)k << 13) | col;
}

// ---------------- x -> i8 ----------------
__global__ __launch_bounds__(256) void quant_x(const float* __restrict__ in,
                                               signed char* __restrict__ out, int n4) {
    int i = blockIdx.x * 256 + threadIdx.x;
    if (i >= n4) return;
    float4 v = ((const float4*)in)[i];
    char4 c;
    c.x = q8(v.x, SX); c.y = q8(v.y, SX); c.z = q8(v.z, SX); c.w = q8(v.w, SX);
    ((char4*)out)[i] = c;
}

// ------- codes = codebook @ W^T (f32) fused with i8 quant + norm partials -------
#define BM 64
#define BN 64
#define BK 16
__global__ __launch_bounds__(256) void codes_gemm_fused(const float* __restrict__ A,
                                                        const float* __restrict__ B,
                                                        float* __restrict__ C,
                                                        signed char* __restrict__ Cq,
                                                        float* __restrict__ Norms) {
    __shared__ float As[BK][BM];
    __shared__ float Bs[BK][BN];
    const int t  = threadIdx.x;
    const int tx = t & 15, ty = t >> 4;
    const int rowBase = blockIdx.x * BM;
    const int colBase = blockIdx.y * BN;
    const int lr = t >> 2;
    const int lk = (t & 3) << 2;

    float4 c0 = make_float4(0,0,0,0), c1 = c0, c2 = c0, c3 = c0;
    const float* Ap = A + (size_t)(rowBase + lr) * DIMK + lk;
    const float* Bp = B + (size_t)(colBase + lr) * DIMK + lk;

    for (int k0 = 0; k0 < DIMK; k0 += BK) {
        float4 av = *(const float4*)(Ap + k0);
        float4 bv = *(const float4*)(Bp + k0);
        As[lk + 0][lr] = av.x; As[lk + 1][lr] = av.y; As[lk + 2][lr] = av.z; As[lk + 3][lr] = av.w;
        Bs[lk + 0][lr] = bv.x; Bs[lk + 1][lr] = bv.y; Bs[lk + 2][lr] = bv.z; Bs[lk + 3][lr] = bv.w;
        __syncthreads();
        #pragma unroll
        for (int k = 0; k < BK; ++k) {
            float4 a = *(const float4*)&As[k][ty << 2];
            float4 b = *(const float4*)&Bs[k][tx << 2];
            c0.x = fmaf(a.x, b.x, c0.x); c0.y = fmaf(a.x, b.y, c0.y); c0.z = fmaf(a.x, b.z, c0.z); c0.w = fmaf(a.x, b.w, c0.w);
            c1.x = fmaf(a.y, b.x, c1.x); c1.y = fmaf(a.y, b.y, c1.y); c1.z = fmaf(a.y, b.z, c1.z); c1.w = fmaf(a.y, b.w, c1.w);
            c2.x = fmaf(a.z, b.x, c2.x); c2.y = fmaf(a.z, b.y, c2.y); c2.z = fmaf(a.z, b.z, c2.z); c2.w = fmaf(a.z, b.w, c2.w);
            c3.x = fmaf(a.w, b.x, c3.x); c3.y = fmaf(a.w, b.y, c3.y); c3.z = fmaf(a.w, b.z, c3.z); c3.w = fmaf(a.w, b.w, c3.w);
        }
        __syncthreads();
    }
    const int r0 = rowBase + (ty << 2);
    const int cc = colBase + (tx << 2);
    #pragma unroll
    for (int i = 0; i < 4; ++i) {
        float4 c = (i == 0) ? c0 : (i == 1) ? c1 : (i == 2) ? c2 : c3;
        const size_t off = (size_t)(r0 + i) * DIMK + cc;
        *(float4*)(C + off) = c;
        char4 q;
        q.x = q8(c.x, SC); q.y = q8(c.y, SC); q.z = q8(c.z, SC); q.w = q8(c.w, SC);
        *(char4*)(Cq + off) = q;
        float s = c.x * c.x + c.y * c.y + c.z * c.z + c.w * c.w;
        s += __shfl_xor(s, 1);
        s += __shfl_xor(s, 2);
        s += __shfl_xor(s, 4);
        s += __shfl_xor(s, 8);
        if (tx == 0) atomicAdd(&Norms[r0 + i], s);
    }
}

// ---------- i8 distance GEMM (MFMA 16x16x64) + ballot candidate emission ----------
// grid: (MROWS/128, CBN/128), 256 threads (4 waves 2x2, each 64x64)
__global__ __launch_bounds__(256) void d2_argmin_i8(
        const signed char* __restrict__ Xq,
        const signed char* __restrict__ Cq,
        const float* __restrict__ Norms,
        unsigned* __restrict__ Cand) {
    __shared__ __align__(16) signed char Ash[128 * 64];
    __shared__ __align__(16) signed char Bsh[128 * 64];

    const int t    = threadIdx.x;
    const int w    = t >> 6;
    const int lane = t & 63;
    const int quad = lane >> 4;
    const int l16  = lane & 15;
    const int wm   = w & 1, wn = w >> 1;
    const int rowBase = blockIdx.x * 128;
    const int colBase = blockIdx.y * 128;

    i32x4 acc[4][4];
    #pragma unroll
    for (int i = 0; i < 4; ++i)
        #pragma unroll
        for (int j = 0; j < 4; ++j)
            acc[i][j] = (i32x4)(0);

    // staging: thread t stages 16 B: row t>>2 (+64 for inst1), k-chunk (t&3)*16
    const int mr = t >> 2;
    const int kc = (t & 3) * 16;
    const size_t gxa = (size_t)(rowBase + mr) * DIMK + kc;
    const size_t gxb = gxa + (size_t)64 * DIMK;
    const size_t gca = (size_t)(colBase + mr) * DIMK + kc;
    const size_t gcb = gca + (size_t)64 * DIMK;
    const int l0 = w * 1024;          // wave-uniform LDS byte base, inst0
    const int l1 = 4096 + w * 1024;   // inst1

    for (int k0 = 0; k0 < DIMK; k0 += 64) {
        load_lds16(Xq + gxa + k0, &Ash[l0]);
        load_lds16(Xq + gxb + k0, &Ash[l1]);
        load_lds16(Cq + gca + k0, &Bsh[l0]);
        load_lds16(Cq + gcb + k0, &Bsh[l1]);
        __syncthreads();

        i32x4 af[4], bf[4];
        #pragma unroll
        for (int i = 0; i < 4; ++i)
            af[i] = *(const i32x4*)&Ash[(wm * 64 + i * 16 + l16) * 64 + quad * 16];
        #pragma unroll
        for (int j = 0; j < 4; ++j)
            bf[j] = *(const i32x4*)&Bsh[(wn * 64 + j * 16 + l16) * 64 + quad * 16];
        #pragma unroll
        for (int i = 0; i < 4; ++i)
            #pragma unroll
            for (int j = 0; j < 4; ++j)
                acc[i][j] = __builtin_amdgcn_mfma_i32_16x16x64_i8(af[i], bf[j], acc[i][j], 0, 0, 0);
        __syncthreads();
    }

    // epilogue: d2 = norm - 2*dot*inv; per quad-row min + ballot emission.
    // C/D layout: col = j*16 + l16, row = i*16 + quad*4 + r
    float nrm[4];
    #pragma unroll
    for (int j = 0; j < 4; ++j)
        nrm[j] = Norms[colBase + wn * 64 + j * 16 + l16];

    const int subtile = blockIdx.y * 2 + wn;                 // 64-col granularity
    const unsigned long long qmask = 0xFFFFull << (quad * 16);
    const unsigned long long ltm = (lane == 0) ? 0ull : (~0ull >> (64 - lane));
    const unsigned colG = colBase + wn * 64 + l16;

    #pragma unroll
    for (int i = 0; i < 4; ++i) {
        #pragma unroll
        for (int r = 0; r < 4; ++r) {
            float d0 = fmaf((float)acc[i][0][r], -2.0f * INV_SS, nrm[0]);
            float d1 = fmaf((float)acc[i][1][r], -2.0f * INV_SS, nrm[1]);
            float d2v = fmaf((float)acc[i][2][r], -2.0f * INV_SS, nrm[2]);
            float d3 = fmaf((float)acc[i][3][r], -2.0f * INV_SS, nrm[3]);
            float mn = fminf(fminf(d0, d1), fminf(d2v, d3));
            mn = fminf(mn, __shfl_xor(mn, 1, 64));
            mn = fminf(mn, __shfl_xor(mn, 2, 64));
            mn = fminf(mn, __shfl_xor(mn, 4, 64));
            mn = fminf(mn, __shfl_xor(mn, 8, 64));
            const float thr = mn + DELTA;
            unsigned long long b0 = __ballot(d0 <= thr);
            unsigned long long b1 = __ballot(d1 <= thr);
            unsigned long long b2 = __ballot(d2v <= thr);
            unsigned long long b3 = __ballot(d3 <= thr);
            const int row = rowBase + wm * 64 + i * 16 + quad * 4 + r;
            unsigned* slot = Cand + ((size_t)row * 128 + subtile) * NSLOT;
            if (d0 <= thr) {
                int rk = __popcll(b0 & qmask & ltm);
                if (rk < NSLOT) slot[rk] = packSlot(d0, colG + 0);
            }
            if (d1 <= thr) {
                int rk = __popcll(b0 & qmask) + __popcll(b1 & qmask & ltm);
                if (rk < NSLOT) slot[rk] = packSlot(d1, colG + 16);
            }
            if (d2v <= thr) {
                int rk = __popcll(b0 & qmask) + __popcll(b1 & qmask)
                       + __popcll(b2 & qmask & ltm);
                if (rk < NSLOT) slot[rk] = packSlot(d2v, colG + 32);
            }
            if (d3 <= thr) {
                int rk = __popcll(b0 & qmask) + __popcll(b1 & qmask)
                       + __popcll(b2 & qmask) + __popcll(b3 & qmask & ltm);
                if (rk < NSLOT) slot[rk] = packSlot(d3, colG + 48);
            }
        }
    }
}

// ---------- refine candidates exactly (f32) + gather + loss partial ----------
// one wave per row; 4 waves / block
__global__ __launch_bounds__(256) void refine_gather(
        const float* __restrict__ X, const float* __restrict__ Codes,
        const float* __restrict__ Norms, const unsigned* __restrict__ Cand,
        float* __restrict__ outQ, float* __restrict__ outIdx,
        float* __restrict__ lossP) {
    const int t    = threadIdx.x;
    const int w    = t >> 6;
    const int lane = t & 63;
    const int row  = blockIdx.x * 4 + w;

    const unsigned* cp = Cand + (size_t)row * 128 * NSLOT + lane * 6;
    unsigned sl[6];
    #pragma unroll
    for (int s = 0; s < 6; ++s) sl[s] = cp[s];

    unsigned mn = sl[0];
    #pragma unroll
    for (int s = 1; s < 6; ++s) mn = min(mn, sl[s]);
    #pragma unroll
    for (int mask = 1; mask < 64; mask <<= 1)
        mn = min(mn, (unsigned)__shfl((int)mn, lane ^ mask, 64));
    const unsigned thrp = (((mn >> 13) + DKEY) << 13) | 0x1FFFu;

    const float4 xa = *(const float4*)(X + (size_t)row * DIMK + lane * 8);
    const float4 xb = *(const float4*)(X + (size_t)row * DIMK + lane * 8 + 4);

    float bestD = __builtin_inff();
    unsigned bestIdx = 0xFFFFFFFFu;

    #pragma unroll
    for (int s = 0; s < 6; ++s) {
        unsigned long long bm = __ballot(sl[s] <= thrp);
        while (bm) {
            const int src = __ffsll(bm) - 1;
            bm &= bm - 1;
            const unsigned sv = (unsigned)__shfl((int)sl[s], src, 64);
            const unsigned idx = sv & 0x1FFFu;
            const float4 ca = *(const float4*)(Codes + (size_t)idx * DIMK + lane * 8);
            const float4 cbv = *(const float4*)(Codes + (size_t)idx * DIMK + lane * 8 + 4);
            float s2 = xa.x * ca.x + xa.y * ca.y + xa.z * ca.z + xa.w * ca.w
                     + xb.x * cbv.x + xb.y * cbv.y + xb.z * cbv.z + xb.w * cbv.w;
            #pragma unroll
            for (int mm = 1; mm < 64; mm <<= 1) s2 += __shfl_xor(s2, mm, 64);
            const float d2 = fmaf(-2.0f, s2, Norms[idx]);
            if (d2 < bestD || (d2 == bestD && idx < bestIdx)) { bestD = d2; bestIdx = idx; }
        }
    }

    // gather quantized + loss partial
    const float4 qa = *(const float4*)(Codes + (size_t)bestIdx * DIMK + lane * 8);
    const float4 qb = *(const float4*)(Codes + (size_t)bestIdx * DIMK + lane * 8 + 4);
    *(float4*)(outQ + (size_t)row * DIMK + lane * 8) = qa;
    *(float4*)(outQ + (size_t)row * DIMK + lane * 8 + 4) = qb;
    float dx0 = xa.x - qa.x, dx1 = xa.y - qa.y, dx2 = xa.z - qa.z, dx3 = xa.w - qa.w;
    float dy0 = xb.x - qb.x, dy1 = xb.y - qb.y, dy2 = xb.z - qb.z, dy3 = xb.w - qb.w;
    float s = dx0 * dx0 + dx1 * dx1 + dx2 * dx2 + dx3 * dx3
            + dy0 * dy0 + dy1 * dy1 + dy2 * dy2 + dy3 * dy3;
    #pragma unroll
    for (int off = 32; off > 0; off >>= 1) s += __shfl_down(s, off);
    if (lane == 0) {
        lossP[row] = s;
        outIdx[row] = (float)bestIdx;
    }
}

// deterministic tree-reduce of 16384 partials
__global__ __launch_bounds__(256) void finalize_loss(const float* __restrict__ lossPartials,
                                                     float* __restrict__ outLoss) {
    const int t = threadIdx.x;
    float s = 0.0f;
    for (int i = t; i < MROWS; i += 256) s += lossPartials[i];
    #pragma unroll
    for (int off = 32; off > 0; off >>= 1) s += __shfl_down(s, off);
    __shared__ float red[4];
    if ((t & 63) == 0) red[t >> 6] = s;
    __syncthreads();
    if (t == 0)
        *outLoss = (red[0] + red[1] + red[2] + red[3]) * (1.0f / (float)((size_t)MROWS * DIMK));
}

extern "C" void kernel_launch(void* const* d_in, const int* in_sizes, int n_in,
                              void* d_out, int out_size, void* d_ws, size_t ws_size,
                              hipStream_t stream) {
    const float* x  = (const float*)d_in[0];   // [16384, 512]
    const float* cb = (const float*)d_in[1];   // [8192, 512]
    const float* W  = (const float*)d_in[2];   // [512, 512]
    float* out = (float*)d_out;

    char* ws = (char*)d_ws;
    float* codes         = (float*)(ws + WS_CODES);
    signed char* xq      = (signed char*)(ws + WS_XQ);
    signed char* cq      = (signed char*)(ws + WS_CQ);
    float* norms         = (float*)(ws + WS_NORMS);
    unsigned* cand       = (unsigned*)(ws + WS_CAND);
    float* lossP         = (float*)(ws + WS_LOSSP);

    hipMemsetAsync(norms, 0, CBN * 4, stream);
    hipMemsetAsync(cand, 0xFF, (size_t)MROWS * 128 * NSLOT * 4, stream);

    // x -> i8
    quant_x<<<(MROWS * DIMK / 4 + 255) / 256, 256, 0, stream>>>(x, xq, MROWS * DIMK / 4);
    // codes = codebook @ W^T (f32) + i8 quant + norms
    codes_gemm_fused<<<dim3(CBN / BM, DIMK / BN), 256, 0, stream>>>(cb, W, codes, cq, norms);
    // i8 MFMA distance + candidate emission
    d2_argmin_i8<<<dim3(MROWS / 128, CBN / 128), 256, 0, stream>>>(xq, cq, norms, cand);
    // exact refine + gather + loss partials
    refine_gather<<<MROWS / 4, 256, 0, stream>>>(x, codes, norms, cand, out,
                                                 out + (size_t)MROWS * DIMK, lossP);
    finalize_loss<<<1, 256, 0, stream>>>(lossP, out + (size_t)MROWS * DIMK + MROWS);
}

// Round 6
// 296.352 us; speedup vs baseline: 7.3889x; 1.3167x over previous
//
#include <hip/hip_runtime.h>

// SimVQ: x[8,2048,512] f32, codebook[8192,512] f32, W[512,512] f32
// out = concat(quantized[16384*512], indices[16384] (as f32), commit_loss[1])
// Rotation-trick forward value == gathered code exactly, so quantized = codes[idx].
//
// Round 6:
//  - d2_argmin_i8: 512 threads / 8 waves, wave-tile 32x64 (acc 32 AGPR) to get
//    under the 128-reg occupancy cliff (R5: 152 regs -> 22% occupancy).
//  - codes pipeline on MFMA (bf16 hi/lo 3-pass), fused f32+i8+norms epilogue.

#define DIMK  512
#define CBN   8192
#define MROWS 16384

#define SX 24.0f
#define SC 500.0f
#define INV_SS (1.0f / (SX * SC))
#define DELTA 0.3f
#define DKEY  1231
#define NSLOT 3

// ws layout (bytes)
#define WS_CODES   0UL          // 8192*512*4    = 16,777,216
#define WS_XQ      16777216UL   // 16384*512     =  8,388,608
#define WS_CQ      25165824UL   // 8192*512      =  4,194,304
#define WS_NORMS   29360128UL   // 8192*4
#define WS_CAND    29392896UL   // 16384*128*3*4 = 25,165,824
#define WS_CBH     29392896UL   // alias: cb hi (consumed before cand memset)
#define WS_CBL     37781504UL   // alias: cb lo
#define WS_WH      54558720UL   // 512*512*2 = 524,288
#define WS_WL      55083008UL
#define WS_LOSSP   55607296UL   // 16384*4
// end ~55.7 MB

typedef short s16x8 __attribute__((ext_vector_type(8)));
typedef int   i32x4 __attribute__((ext_vector_type(4)));
typedef float f32x4 __attribute__((ext_vector_type(4)));

__device__ __forceinline__ unsigned short f2bf(float f) {
    unsigned u = __float_as_uint(f);
    unsigned r = u + 0x7FFFu + ((u >> 16) & 1u);   // RTNE
    return (unsigned short)(r >> 16);
}
__device__ __forceinline__ float bf2f(unsigned short h) {
    return __uint_as_float(((unsigned)h) << 16);
}
__device__ __forceinline__ void load_lds16(const void* g, void* l) {
    __builtin_amdgcn_global_load_lds((const __attribute__((address_space(1))) void*)g,
                                     (__attribute__((address_space(3))) void*)l,
                                     16, 0, 0);
}
__device__ __forceinline__ signed char q8(float v, float s) {
    return (signed char)__float2int_rn(fminf(fmaxf(v * s, -127.0f), 127.0f));
}
__device__ __forceinline__ unsigned packSlot(float d, unsigned col) {
    int k = (int)((d + 16.0f) * 4096.0f);
    k = k < 0 ? 0 : (k > 524287 ? 524287 : k);
    return ((unsigned)k << 13) | col;
}

// ---------------- f32 -> bf16 hi + lo ----------------
__global__ __launch_bounds__(256) void split_bf16(const float* __restrict__ in,
                                                  unsigned short* __restrict__ hi,
                                                  unsigned short* __restrict__ lo,
                                                  int n4) {
    int i = blockIdx.x * 256 + threadIdx.x;
    if (i >= n4) return;
    float4 v = ((const float4*)in)[i];
    ushort4 h, l;
    h.x = f2bf(v.x); l.x = f2bf(v.x - bf2f(h.x));
    h.y = f2bf(v.y); l.y = f2bf(v.y - bf2f(h.y));
    h.z = f2bf(v.z); l.z = f2bf(v.z - bf2f(h.z));
    h.w = f2bf(v.w); l.w = f2bf(v.w - bf2f(h.w));
    ((ushort4*)hi)[i] = h;
    ((ushort4*)lo)[i] = l;
}

// ---------------- x -> i8 ----------------
__global__ __launch_bounds__(256) void quant_x(const float* __restrict__ in,
                                               signed char* __restrict__ out, int n4) {
    int i = blockIdx.x * 256 + threadIdx.x;
    if (i >= n4) return;
    float4 v = ((const float4*)in)[i];
    char4 c;
    c.x = q8(v.x, SX); c.y = q8(v.y, SX); c.z = q8(v.z, SX); c.w = q8(v.w, SX);
    ((char4*)out)[i] = c;
}

// ------ codes = cb @ W^T via bf16 hi/lo 3-pass MFMA; emit f32 + i8 + norms ------
// grid (CBN/128, 512/128) = (64,4), 256 threads (4 waves 2x2 of 64x64)
__global__ __launch_bounds__(256) void codes_mfma(
        const unsigned short* __restrict__ Ah_g, const unsigned short* __restrict__ Al_g,
        const unsigned short* __restrict__ Bh_g, const unsigned short* __restrict__ Bl_g,
        float* __restrict__ C, signed char* __restrict__ Cq, float* __restrict__ Norms) {
    __shared__ __align__(16) unsigned short Ahi[128 * 32];
    __shared__ __align__(16) unsigned short Alo[128 * 32];
    __shared__ __align__(16) unsigned short Bhi[128 * 32];
    __shared__ __align__(16) unsigned short Blo[128 * 32];

    const int t    = threadIdx.x;
    const int w    = t >> 6;
    const int lane = t & 63;
    const int quad = lane >> 4;
    const int l16  = lane & 15;
    const int wm   = w & 1, wn = w >> 1;
    const int rowBase = blockIdx.x * 128;
    const int colBase = blockIdx.y * 128;

    f32x4 acc[4][4];
    #pragma unroll
    for (int i = 0; i < 4; ++i)
        #pragma unroll
        for (int j = 0; j < 4; ++j)
            acc[i][j] = (f32x4)(0.0f);

    const int mr = t >> 2;
    const int kq = (t & 3) * 8;
    const size_t gxa = (size_t)(rowBase + mr) * DIMK + kq;
    const size_t gxb = gxa + (size_t)64 * DIMK;
    const size_t gca = (size_t)(colBase + mr) * DIMK + kq;
    const size_t gcb = gca + (size_t)64 * DIMK;
    const int l0 = w * 512;
    const int l1 = 2048 + w * 512;

    for (int k0 = 0; k0 < DIMK; k0 += 32) {
        load_lds16(Ah_g + gxa + k0, &Ahi[l0]);
        load_lds16(Ah_g + gxb + k0, &Ahi[l1]);
        load_lds16(Al_g + gxa + k0, &Alo[l0]);
        load_lds16(Al_g + gxb + k0, &Alo[l1]);
        load_lds16(Bh_g + gca + k0, &Bhi[l0]);
        load_lds16(Bh_g + gcb + k0, &Bhi[l1]);
        load_lds16(Bl_g + gca + k0, &Blo[l0]);
        load_lds16(Bl_g + gcb + k0, &Blo[l1]);
        __syncthreads();

        s16x8 ah[4], al[4], bh[4], bl[4];
        #pragma unroll
        for (int i = 0; i < 4; ++i) {
            const int m = wm * 64 + i * 16 + l16;
            ah[i] = *(const s16x8*)&Ahi[m * 32 + quad * 8];
            al[i] = *(const s16x8*)&Alo[m * 32 + quad * 8];
        }
        #pragma unroll
        for (int j = 0; j < 4; ++j) {
            const int n = wn * 64 + j * 16 + l16;
            bh[j] = *(const s16x8*)&Bhi[n * 32 + quad * 8];
            bl[j] = *(const s16x8*)&Blo[n * 32 + quad * 8];
        }
        #pragma unroll
        for (int i = 0; i < 4; ++i)
            #pragma unroll
            for (int j = 0; j < 4; ++j) {
                acc[i][j] = __builtin_amdgcn_mfma_f32_16x16x32_bf16(ah[i], bh[j], acc[i][j], 0, 0, 0);
                acc[i][j] = __builtin_amdgcn_mfma_f32_16x16x32_bf16(ah[i], bl[j], acc[i][j], 0, 0, 0);
                acc[i][j] = __builtin_amdgcn_mfma_f32_16x16x32_bf16(al[i], bh[j], acc[i][j], 0, 0, 0);
            }
        __syncthreads();
    }

    // epilogue: C/D layout col = j*16+l16, row = i*16+quad*4+r
    #pragma unroll
    for (int i = 0; i < 4; ++i) {
        #pragma unroll
        for (int r = 0; r < 4; ++r) {
            const int row = rowBase + wm * 64 + i * 16 + quad * 4 + r;
            float nsum = 0.0f;
            #pragma unroll
            for (int j = 0; j < 4; ++j) {
                const int col = colBase + wn * 64 + j * 16 + l16;
                const float v = acc[i][j][r];
                C[(size_t)row * DIMK + col] = v;
                Cq[(size_t)row * DIMK + col] = q8(v, SC);
                nsum = fmaf(v, v, nsum);
            }
            nsum += __shfl_xor(nsum, 1, 64);
            nsum += __shfl_xor(nsum, 2, 64);
            nsum += __shfl_xor(nsum, 4, 64);
            nsum += __shfl_xor(nsum, 8, 64);
            if (l16 == 0) atomicAdd(&Norms[row], nsum);
        }
    }
}

// ---------- i8 distance GEMM (MFMA 16x16x64) + ballot candidate emission ----------
// grid: (MROWS/128, CBN/128), 512 threads = 8 waves: wm in 0..3 (32 rows), wn in 0..1 (64 cols)
__global__ __launch_bounds__(512) void d2_argmin_i8(
        const signed char* __restrict__ Xq,
        const signed char* __restrict__ Cq,
        const float* __restrict__ Norms,
        unsigned* __restrict__ Cand) {
    __shared__ __align__(16) signed char Ash[128 * 64];
    __shared__ __align__(16) signed char Bsh[128 * 64];

    const int t    = threadIdx.x;
    const int w    = t >> 6;
    const int lane = t & 63;
    const int quad = lane >> 4;
    const int l16  = lane & 15;
    const int wm   = w & 3, wn = w >> 2;
    const int rowBase = blockIdx.x * 128;
    const int colBase = blockIdx.y * 128;

    i32x4 acc[2][4];
    #pragma unroll
    for (int i = 0; i < 2; ++i)
        #pragma unroll
        for (int j = 0; j < 4; ++j)
            acc[i][j] = (i32x4)(0);

    // staging: 512 threads stage A(128x64) and B(128x64) in one inst each
    const int mr = t >> 2;            // 0..127
    const int kc = (t & 3) * 16;
    const size_t gxa = (size_t)(rowBase + mr) * DIMK + kc;
    const size_t gca = (size_t)(colBase + mr) * DIMK + kc;
    const int lb = w * 1024;          // wave-uniform LDS byte base

    for (int k0 = 0; k0 < DIMK; k0 += 64) {
        load_lds16(Xq + gxa + k0, &Ash[lb]);
        load_lds16(Cq + gca + k0, &Bsh[lb]);
        __syncthreads();

        i32x4 af[2], bf[4];
        #pragma unroll
        for (int i = 0; i < 2; ++i)
            af[i] = *(const i32x4*)&Ash[(wm * 32 + i * 16 + l16) * 64 + quad * 16];
        #pragma unroll
        for (int j = 0; j < 4; ++j)
            bf[j] = *(const i32x4*)&Bsh[(wn * 64 + j * 16 + l16) * 64 + quad * 16];
        #pragma unroll
        for (int i = 0; i < 2; ++i)
            #pragma unroll
            for (int j = 0; j < 4; ++j)
                acc[i][j] = __builtin_amdgcn_mfma_i32_16x16x64_i8(af[i], bf[j], acc[i][j], 0, 0, 0);
        __syncthreads();
    }

    // epilogue: d2 = norm - 2*dot*inv; per quad-row min + ballot emission.
    float nrm[4];
    #pragma unroll
    for (int j = 0; j < 4; ++j)
        nrm[j] = Norms[colBase + wn * 64 + j * 16 + l16];

    const int subtile = blockIdx.y * 2 + wn;
    const unsigned long long qmask = 0xFFFFull << (quad * 16);
    const unsigned long long ltm = (lane == 0) ? 0ull : (~0ull >> (64 - lane));
    const unsigned colG = colBase + wn * 64 + l16;

    #pragma unroll
    for (int i = 0; i < 2; ++i) {
        #pragma unroll
        for (int r = 0; r < 4; ++r) {
            float d0 = fmaf((float)acc[i][0][r], -2.0f * INV_SS, nrm[0]);
            float d1 = fmaf((float)acc[i][1][r], -2.0f * INV_SS, nrm[1]);
            float d2v = fmaf((float)acc[i][2][r], -2.0f * INV_SS, nrm[2]);
            float d3 = fmaf((float)acc[i][3][r], -2.0f * INV_SS, nrm[3]);
            float mn = fminf(fminf(d0, d1), fminf(d2v, d3));
            mn = fminf(mn, __shfl_xor(mn, 1, 64));
            mn = fminf(mn, __shfl_xor(mn, 2, 64));
            mn = fminf(mn, __shfl_xor(mn, 4, 64));
            mn = fminf(mn, __shfl_xor(mn, 8, 64));
            const float thr = mn + DELTA;
            unsigned long long b0 = __ballot(d0 <= thr);
            unsigned long long b1 = __ballot(d1 <= thr);
            unsigned long long b2 = __ballot(d2v <= thr);
            unsigned long long b3 = __ballot(d3 <= thr);
            const int row = rowBase + wm * 32 + i * 16 + quad * 4 + r;
            unsigned* slot = Cand + ((size_t)row * 128 + subtile) * NSLOT;
            if (d0 <= thr) {
                int rk = __popcll(b0 & qmask & ltm);
                if (rk < NSLOT) slot[rk] = packSlot(d0, colG + 0);
            }
            if (d1 <= thr) {
                int rk = __popcll(b0 & qmask) + __popcll(b1 & qmask & ltm);
                if (rk < NSLOT) slot[rk] = packSlot(d1, colG + 16);
            }
            if (d2v <= thr) {
                int rk = __popcll(b0 & qmask) + __popcll(b1 & qmask)
                       + __popcll(b2 & qmask & ltm);
                if (rk < NSLOT) slot[rk] = packSlot(d2v, colG + 32);
            }
            if (d3 <= thr) {
                int rk = __popcll(b0 & qmask) + __popcll(b1 & qmask)
                       + __popcll(b2 & qmask) + __popcll(b3 & qmask & ltm);
                if (rk < NSLOT) slot[rk] = packSlot(d3, colG + 48);
            }
        }
    }
}

// ---------- refine candidates exactly (f32) + gather + loss partial ----------
__global__ __launch_bounds__(256) void refine_gather(
        const float* __restrict__ X, const float* __restrict__ Codes,
        const float* __restrict__ Norms, const unsigned* __restrict__ Cand,
        float* __restrict__ outQ, float* __restrict__ outIdx,
        float* __restrict__ lossP) {
    const int t    = threadIdx.x;
    const int w    = t >> 6;
    const int lane = t & 63;
    const int row  = blockIdx.x * 4 + w;

    const unsigned* cp = Cand + (size_t)row * 128 * NSLOT + lane * 6;
    unsigned sl[6];
    #pragma unroll
    for (int s = 0; s < 6; ++s) sl[s] = cp[s];

    unsigned mn = sl[0];
    #pragma unroll
    for (int s = 1; s < 6; ++s) mn = min(mn, sl[s]);
    #pragma unroll
    for (int mask = 1; mask < 64; mask <<= 1)
        mn = min(mn, (unsigned)__shfl((int)mn, lane ^ mask, 64));
    const unsigned thrp = (((mn >> 13) + DKEY) << 13) | 0x1FFFu;

    const float4 xa = *(const float4*)(X + (size_t)row * DIMK + lane * 8);
    const float4 xb = *(const float4*)(X + (size_t)row * DIMK + lane * 8 + 4);

    float bestD = __builtin_inff();
    unsigned bestIdx = 0xFFFFFFFFu;

    #pragma unroll
    for (int s = 0; s < 6; ++s) {
        unsigned long long bm = __ballot(sl[s] <= thrp);
        while (bm) {
            const int src = __ffsll(bm) - 1;
            bm &= bm - 1;
            const unsigned sv = (unsigned)__shfl((int)sl[s], src, 64);
            const unsigned idx = sv & 0x1FFFu;
            const float4 ca = *(const float4*)(Codes + (size_t)idx * DIMK + lane * 8);
            const float4 cbv = *(const float4*)(Codes + (size_t)idx * DIMK + lane * 8 + 4);
            float s2 = xa.x * ca.x + xa.y * ca.y + xa.z * ca.z + xa.w * ca.w
                     + xb.x * cbv.x + xb.y * cbv.y + xb.z * cbv.z + xb.w * cbv.w;
            #pragma unroll
            for (int mm = 1; mm < 64; mm <<= 1) s2 += __shfl_xor(s2, mm, 64);
            const float d2 = fmaf(-2.0f, s2, Norms[idx]);
            if (d2 < bestD || (d2 == bestD && idx < bestIdx)) { bestD = d2; bestIdx = idx; }
        }
    }

    const float4 qa = *(const float4*)(Codes + (size_t)bestIdx * DIMK + lane * 8);
    const float4 qb = *(const float4*)(Codes + (size_t)bestIdx * DIMK + lane * 8 + 4);
    *(float4*)(outQ + (size_t)row * DIMK + lane * 8) = qa;
    *(float4*)(outQ + (size_t)row * DIMK + lane * 8 + 4) = qb;
    float dx0 = xa.x - qa.x, dx1 = xa.y - qa.y, dx2 = xa.z - qa.z, dx3 = xa.w - qa.w;
    float dy0 = xb.x - qb.x, dy1 = xb.y - qb.y, dy2 = xb.z - qb.z, dy3 = xb.w - qb.w;
    float s = dx0 * dx0 + dx1 * dx1 + dx2 * dx2 + dx3 * dx3
            + dy0 * dy0 + dy1 * dy1 + dy2 * dy2 + dy3 * dy3;
    #pragma unroll
    for (int off = 32; off > 0; off >>= 1) s += __shfl_down(s, off);
    if (lane == 0) {
        lossP[row] = s;
        outIdx[row] = (float)bestIdx;
    }
}

__global__ __launch_bounds__(256) void finalize_loss(const float* __restrict__ lossPartials,
                                                     float* __restrict__ outLoss) {
    const int t = threadIdx.x;
    float s = 0.0f;
    for (int i = t; i < MROWS; i += 256) s += lossPartials[i];
    #pragma unroll
    for (int off = 32; off > 0; off >>= 1) s += __shfl_down(s, off);
    __shared__ float red[4];
    if ((t & 63) == 0) red[t >> 6] = s;
    __syncthreads();
    if (t == 0)
        *outLoss = (red[0] + red[1] + red[2] + red[3]) * (1.0f / (float)((size_t)MROWS * DIMK));
}

extern "C" void kernel_launch(void* const* d_in, const int* in_sizes, int n_in,
                              void* d_out, int out_size, void* d_ws, size_t ws_size,
                              hipStream_t stream) {
    const float* x  = (const float*)d_in[0];
    const float* cb = (const float*)d_in[1];
    const float* W  = (const float*)d_in[2];
    float* out = (float*)d_out;

    char* ws = (char*)d_ws;
    float* codes          = (float*)(ws + WS_CODES);
    signed char* xq       = (signed char*)(ws + WS_XQ);
    signed char* cq       = (signed char*)(ws + WS_CQ);
    float* norms          = (float*)(ws + WS_NORMS);
    unsigned* cand        = (unsigned*)(ws + WS_CAND);
    unsigned short* cbh   = (unsigned short*)(ws + WS_CBH);   // aliases cand
    unsigned short* cbl   = (unsigned short*)(ws + WS_CBL);   // aliases cand
    unsigned short* wh    = (unsigned short*)(ws + WS_WH);
    unsigned short* wl    = (unsigned short*)(ws + WS_WL);
    float* lossP          = (float*)(ws + WS_LOSSP);

    hipMemsetAsync(norms, 0, CBN * 4, stream);

    // splits (cbh/cbl live in the cand region; consumed by codes_mfma below)
    split_bf16<<<(CBN * DIMK / 4 + 255) / 256, 256, 0, stream>>>(cb, cbh, cbl, CBN * DIMK / 4);
    split_bf16<<<(DIMK * DIMK / 4 + 255) / 256, 256, 0, stream>>>(W, wh, wl, DIMK * DIMK / 4);
    quant_x<<<(MROWS * DIMK / 4 + 255) / 256, 256, 0, stream>>>(x, xq, MROWS * DIMK / 4);

    // codes = cb @ W^T (3-pass hi/lo MFMA) -> f32 codes + i8 cq + norms
    codes_mfma<<<dim3(CBN / 128, DIMK / 128), 256, 0, stream>>>(cbh, cbl, wh, wl, codes, cq, norms);

    // cand init AFTER codes_mfma (cbh/cbl alias this region)
    hipMemsetAsync(cand, 0xFF, (size_t)MROWS * 128 * NSLOT * 4, stream);

    // i8 MFMA distance + candidate emission
    d2_argmin_i8<<<dim3(MROWS / 128, CBN / 128), 512, 0, stream>>>(xq, cq, norms, cand);

    // exact refine + gather + loss partials
    refine_gather<<<MROWS / 4, 256, 0, stream>>>(x, codes, norms, cand, out,
                                                 out + (size_t)MROWS * DIMK, lossP);
    finalize_loss<<<1, 256, 0, stream>>>(lossP, out + (size_t)MROWS * DIMK + MROWS);
}